// Round 1
// baseline (3406.975 us; speedup 1.0000x reference)
//
#include <hip/hip_runtime.h>
#include <math.h>

#define H_IMG 224
#define W_IMG 224
#define EPSF 1e-8f
#define NV 6890
#define NF 13776
#define NB 2
#define FCHUNK 256
#define NCHUNK ((NF + FCHUNK - 1) / FCHUNK)   // 54
#define FPAD (NCHUNK * FCHUNK)                // 13824

// Per-face record: 20 floats = 5 float4 = 80 B
//  q0: e0x, e0y, a0x, a0y   (edge for w0 = e0x*(py-a0y) - e0y*(px-a0x))
//  q1: e1x, e1y, a1x, a1y
//  q2: e2x, e2y, a2x, a2y
//  q3: z0, z1, z2, inv_area (z = 1e30 sentinel if face invalid)
//  q4: bxmin, bxmax, bymin, bymax
struct __align__(16) FaceRec { float4 q[5]; };

__global__ void proj_kernel(const float* __restrict__ v,
                            const float* __restrict__ cf,
                            const float* __restrict__ cc,
                            const float* __restrict__ ct,
                            const float* __restrict__ crt,
                            float4* __restrict__ verts) {
  int i = blockIdx.x * blockDim.x + threadIdx.x;
  if (i >= NB * NV) return;
  // Rodrigues (exact-on-zeros path: th=1e-6, k=0, c=1 -> R=I)
  float r0 = crt[0], r1 = crt[1], r2 = crt[2];
  float ss = __fadd_rn(__fadd_rn(__fmul_rn(r0, r0), __fmul_rn(r1, r1)), __fmul_rn(r2, r2));
  float th = sqrtf(__fadd_rn(ss, 1e-12f));
  float kx = r0 / th, ky = r1 / th, kz = r2 / th;
  float c = cosf(th), s = sinf(th), oc = 1.0f - c;
  float R00 = c + oc * kx * kx,      R01 = oc * kx * ky - s * kz, R02 = oc * kx * kz + s * ky;
  float R10 = oc * ky * kx + s * kz, R11 = c + oc * ky * ky,      R12 = oc * ky * kz - s * kx;
  float R20 = oc * kz * kx - s * ky, R21 = oc * kz * ky + s * kx, R22 = c + oc * kz * kz;
  float x = v[i * 3 + 0], y = v[i * 3 + 1], z = v[i * 3 + 2];
  float xc = R00 * x + R01 * y + R02 * z + ct[0];
  float yc = R10 * x + R11 * y + R12 * z + ct[1];
  float zc = R20 * x + R21 * y + R22 * z + ct[2];
  float zs = fmaxf(zc, EPSF);
  // u = (x/zs)*fx + cx, each op rounded separately (match numpy fp32)
  float u = __fadd_rn(__fmul_rn(xc / zs, cf[0]), cc[0]);
  float w = __fadd_rn(__fmul_rn(yc / zs, cf[1]), cc[1]);
  verts[i] = make_float4(u, w, zc, 0.0f);
}

__global__ void face_kernel(const int* __restrict__ f,
                            const float4* __restrict__ verts,
                            FaceRec* __restrict__ recs) {
  int i = blockIdx.x * blockDim.x + threadIdx.x;
  if (i >= NB * FPAD) return;
  int b = i / FPAD, fi = i - b * FPAD;
  FaceRec r;
  if (fi >= NF) {
    r.q[0] = make_float4(0.f, 0.f, 0.f, 0.f);
    r.q[1] = make_float4(0.f, 0.f, 0.f, 0.f);
    r.q[2] = make_float4(0.f, 0.f, 0.f, 0.f);
    r.q[3] = make_float4(1e30f, 1e30f, 1e30f, 0.f);
    r.q[4] = make_float4(1e30f, -1e30f, 1e30f, -1e30f);  // bbox always misses
  } else {
    int i0 = f[fi * 3 + 0], i1 = f[fi * 3 + 1], i2 = f[fi * 3 + 2];
    float4 p0 = verts[b * NV + i0];
    float4 p1 = verts[b * NV + i1];
    float4 p2 = verts[b * NV + i2];
    float x0 = p0.x, y0 = p0.y, z0 = p0.z;
    float x1 = p1.x, y1 = p1.y, z1 = p1.z;
    float x2 = p2.x, y2 = p2.y, z2 = p2.z;
    // area = (x1-x0)*(y2-y0) - (y1-y0)*(x2-x0), exact op order, no FMA contraction
    float area = __fsub_rn(__fmul_rn(__fsub_rn(x1, x0), __fsub_rn(y2, y0)),
                           __fmul_rn(__fsub_rn(y1, y0), __fsub_rn(x2, x0)));
    bool nz = fabsf(area) > EPSF;
    float inv_area = nz ? (1.0f / area) : 0.0f;
    bool zv = (z0 > EPSF) && (z1 > EPSF) && (z2 > EPSF);
    bool ok = nz && zv;
    float zz0 = ok ? fmaxf(z0, EPSF) : 1e30f;
    float zz1 = ok ? fmaxf(z1, EPSF) : 1e30f;
    float zz2 = ok ? fmaxf(z2, EPSF) : 1e30f;
    r.q[0] = make_float4(__fsub_rn(x2, x1), __fsub_rn(y2, y1), x1, y1);
    r.q[1] = make_float4(__fsub_rn(x0, x2), __fsub_rn(y0, y2), x2, y2);
    r.q[2] = make_float4(__fsub_rn(x1, x0), __fsub_rn(y1, y0), x0, y0);
    r.q[3] = make_float4(zz0, zz1, zz2, inv_area);
    r.q[4] = make_float4(fminf(fminf(x0, x1), x2), fmaxf(fmaxf(x0, x1), x2),
                         fminf(fminf(y0, y1), y2), fmaxf(fmaxf(y0, y1), y2));
  }
  recs[i] = r;
}

__global__ __launch_bounds__(256) void raster_kernel(
    const FaceRec* __restrict__ recs, const int* __restrict__ f,
    const float* __restrict__ vc, const float* __restrict__ bg,
    float* __restrict__ out) {
  __shared__ float4 lds4[FCHUNK * 5];  // 20 KB
  int b = blockIdx.z;
  int x = blockIdx.x * 16 + threadIdx.x;
  int y = blockIdx.y * 16 + threadIdx.y;
  float px = (float)x + 0.5f, py = (float)y + 0.5f;
  const FaceRec* rb = recs + (size_t)b * FPAD;
  const float4* src_base = (const float4*)rb;
  int tid = threadIdx.y * 16 + threadIdx.x;

  float best_zp = INFINITY;
  int best = -1;

  for (int ch = 0; ch < NCHUNK; ++ch) {
    const float4* src = src_base + (size_t)ch * FCHUNK * 5;
    #pragma unroll
    for (int j = 0; j < 5; ++j) lds4[tid + j * 256] = src[tid + j * 256];
    __syncthreads();
    int base = ch * FCHUNK;
    for (int i = 0; i < FCHUNK; ++i) {
      float4 q4 = lds4[i * 5 + 4];
      if (px < q4.x || px > q4.y || py < q4.z || py > q4.w) continue;
      float4 q0 = lds4[i * 5 + 0];
      float4 q1 = lds4[i * 5 + 1];
      float4 q2 = lds4[i * 5 + 2];
      float4 q3 = lds4[i * 5 + 3];
      // w_k = e_kx*(py-a_ky) - e_ky*(px-a_kx), exact fp32 op order
      float w0 = __fsub_rn(__fmul_rn(q0.x, __fsub_rn(py, q0.w)),
                           __fmul_rn(q0.y, __fsub_rn(px, q0.z)));
      float w1 = __fsub_rn(__fmul_rn(q1.x, __fsub_rn(py, q1.w)),
                           __fmul_rn(q1.y, __fsub_rn(px, q1.z)));
      float w2 = __fsub_rn(__fmul_rn(q2.x, __fsub_rn(py, q2.w)),
                           __fmul_rn(q2.y, __fsub_rn(px, q2.z)));
      float b0 = __fmul_rn(w0, q3.w);
      float b1 = __fmul_rn(w1, q3.w);
      float b2 = __fmul_rn(w2, q3.w);
      if (b0 >= 0.0f && b1 >= 0.0f && b2 >= 0.0f) {
        // inv_z = b0/z0 + b1/z1 + b2/z2, true IEEE divides, left-assoc adds
        float invz = __fadd_rn(__fadd_rn(b0 / q3.x, b1 / q3.y), b2 / q3.z);
        if (invz > EPSF) {
          float zp = 1.0f / invz;
          if (zp < best_zp) { best_zp = zp; best = base + i; }  // strict <: first index wins ties
        }
      }
    }
    __syncthreads();
  }

  float o0, o1, o2;
  if (best >= 0) {
    const float* q = (const float*)(rb + best);
    float w0 = __fsub_rn(__fmul_rn(q[0], __fsub_rn(py, q[3])),
                         __fmul_rn(q[1], __fsub_rn(px, q[2])));
    float w1 = __fsub_rn(__fmul_rn(q[4], __fsub_rn(py, q[7])),
                         __fmul_rn(q[5], __fsub_rn(px, q[6])));
    float w2 = __fsub_rn(__fmul_rn(q[8], __fsub_rn(py, q[11])),
                         __fmul_rn(q[9], __fsub_rn(px, q[10])));
    float ia = q[15];
    float b0 = __fmul_rn(w0, ia), b1 = __fmul_rn(w1, ia), b2 = __fmul_rn(w2, ia);
    float pc0 = b0 / q[12], pc1 = b1 / q[13], pc2 = b2 / q[14];
    int i0 = f[best * 3 + 0], i1 = f[best * 3 + 1], i2 = f[best * 3 + 2];
    const float* c0p = vc + (size_t)i0 * 3;
    const float* c1p = vc + (size_t)i1 * 3;
    const float* c2p = vc + (size_t)i2 * 3;
    // col_c = (pc0*c0 + pc1*c1 + pc2*c2) * zmin, left-assoc like einsum
    o0 = __fmul_rn(__fadd_rn(__fadd_rn(__fmul_rn(pc0, c0p[0]), __fmul_rn(pc1, c1p[0])),
                             __fmul_rn(pc2, c2p[0])), best_zp);
    o1 = __fmul_rn(__fadd_rn(__fadd_rn(__fmul_rn(pc0, c0p[1]), __fmul_rn(pc1, c1p[1])),
                             __fmul_rn(pc2, c2p[1])), best_zp);
    o2 = __fmul_rn(__fadd_rn(__fadd_rn(__fmul_rn(pc0, c0p[2]), __fmul_rn(pc1, c1p[2])),
                             __fmul_rn(pc2, c2p[2])), best_zp);
  } else {
    o0 = bg[0]; o1 = bg[1]; o2 = bg[2];
  }
  size_t o = ((size_t)(b * H_IMG + y) * W_IMG + x) * 3;
  out[o + 0] = o0;
  out[o + 1] = o1;
  out[o + 2] = o2;
}

extern "C" void kernel_launch(void* const* d_in, const int* in_sizes, int n_in,
                              void* d_out, int out_size, void* d_ws, size_t ws_size,
                              hipStream_t stream) {
  const float* v   = (const float*)d_in[0];
  const float* vc  = (const float*)d_in[1];
  const float* bg  = (const float*)d_in[2];
  const float* cf  = (const float*)d_in[3];
  const float* cc  = (const float*)d_in[4];
  const float* ct  = (const float*)d_in[5];
  const float* crt = (const float*)d_in[6];
  const int*   f   = (const int*)d_in[7];
  float* out = (float*)d_out;

  float4*  verts = (float4*)d_ws;                      // NB*NV*16 B = 220,480 B
  FaceRec* recs  = (FaceRec*)((char*)d_ws + 262144);   // NB*FPAD*80 B = 2,211,840 B

  hipLaunchKernelGGL(proj_kernel, dim3((NB * NV + 255) / 256), dim3(256), 0, stream,
                     v, cf, cc, ct, crt, verts);
  hipLaunchKernelGGL(face_kernel, dim3(NB * FPAD / 256), dim3(256), 0, stream,
                     f, verts, recs);
  hipLaunchKernelGGL(raster_kernel, dim3(W_IMG / 16, H_IMG / 16, NB), dim3(16, 16), 0, stream,
                     recs, f, vc, bg, out);
}

// Round 2
// 878.353 us; speedup vs baseline: 3.8788x; 3.8788x over previous
//
#include <hip/hip_runtime.h>
#include <math.h>

#define H_IMG 224
#define W_IMG 224
#define HW (H_IMG * W_IMG)
#define EPSF 1e-8f
#define NV 6890
#define NF 13776
#define NB 2
#define FCHUNK 256
#define NCHUNK ((NF + FCHUNK - 1) / FCHUNK)   // 54
#define FPAD (NCHUNK * FCHUNK)                // 13824
#define NSPLIT 9
#define CH_PER_SPLIT (NCHUNK / NSPLIT)        // 6

// Per-face record: 20 floats = 5 float4 = 80 B
//  q0: e0x, e0y, a0x, a0y   (edge for w0 = e0x*(py-a0y) - e0y*(px-a0x))
//  q1: e1x, e1y, a1x, a1y
//  q2: e2x, e2y, a2x, a2y
//  q3: z0, z1, z2, inv_area (z = 1e30 sentinel if face invalid)
//  q4: bxmin, bxmax, bymin, bymax
struct __align__(16) FaceRec { float4 q[5]; };

__global__ void proj_kernel(const float* __restrict__ v,
                            const float* __restrict__ cf,
                            const float* __restrict__ cc,
                            const float* __restrict__ ct,
                            const float* __restrict__ crt,
                            float4* __restrict__ verts) {
  int i = blockIdx.x * blockDim.x + threadIdx.x;
  if (i >= NB * NV) return;
  float r0 = crt[0], r1 = crt[1], r2 = crt[2];
  float ss = __fadd_rn(__fadd_rn(__fmul_rn(r0, r0), __fmul_rn(r1, r1)), __fmul_rn(r2, r2));
  float th = sqrtf(__fadd_rn(ss, 1e-12f));
  float kx = r0 / th, ky = r1 / th, kz = r2 / th;
  float c = cosf(th), s = sinf(th), oc = 1.0f - c;
  float R00 = c + oc * kx * kx,      R01 = oc * kx * ky - s * kz, R02 = oc * kx * kz + s * ky;
  float R10 = oc * ky * kx + s * kz, R11 = c + oc * ky * ky,      R12 = oc * ky * kz - s * kx;
  float R20 = oc * kz * kx - s * ky, R21 = oc * kz * ky + s * kx, R22 = c + oc * kz * kz;
  float x = v[i * 3 + 0], y = v[i * 3 + 1], z = v[i * 3 + 2];
  float xc = R00 * x + R01 * y + R02 * z + ct[0];
  float yc = R10 * x + R11 * y + R12 * z + ct[1];
  float zc = R20 * x + R21 * y + R22 * z + ct[2];
  float zs = fmaxf(zc, EPSF);
  float u = __fadd_rn(__fmul_rn(xc / zs, cf[0]), cc[0]);
  float w = __fadd_rn(__fmul_rn(yc / zs, cf[1]), cc[1]);
  verts[i] = make_float4(u, w, zc, 0.0f);
}

__global__ void face_kernel(const int* __restrict__ f,
                            const float4* __restrict__ verts,
                            FaceRec* __restrict__ recs) {
  int i = blockIdx.x * blockDim.x + threadIdx.x;
  if (i >= NB * FPAD) return;
  int b = i / FPAD, fi = i - b * FPAD;
  FaceRec r;
  if (fi >= NF) {
    r.q[0] = make_float4(0.f, 0.f, 0.f, 0.f);
    r.q[1] = make_float4(0.f, 0.f, 0.f, 0.f);
    r.q[2] = make_float4(0.f, 0.f, 0.f, 0.f);
    r.q[3] = make_float4(1e30f, 1e30f, 1e30f, 0.f);
    r.q[4] = make_float4(1e30f, -1e30f, 1e30f, -1e30f);  // bbox always misses
  } else {
    int i0 = f[fi * 3 + 0], i1 = f[fi * 3 + 1], i2 = f[fi * 3 + 2];
    float4 p0 = verts[b * NV + i0];
    float4 p1 = verts[b * NV + i1];
    float4 p2 = verts[b * NV + i2];
    float x0 = p0.x, y0 = p0.y, z0 = p0.z;
    float x1 = p1.x, y1 = p1.y, z1 = p1.z;
    float x2 = p2.x, y2 = p2.y, z2 = p2.z;
    float area = __fsub_rn(__fmul_rn(__fsub_rn(x1, x0), __fsub_rn(y2, y0)),
                           __fmul_rn(__fsub_rn(y1, y0), __fsub_rn(x2, x0)));
    bool nz = fabsf(area) > EPSF;
    float inv_area = nz ? (1.0f / area) : 0.0f;
    bool zv = (z0 > EPSF) && (z1 > EPSF) && (z2 > EPSF);
    bool ok = nz && zv;
    float zz0 = ok ? fmaxf(z0, EPSF) : 1e30f;
    float zz1 = ok ? fmaxf(z1, EPSF) : 1e30f;
    float zz2 = ok ? fmaxf(z2, EPSF) : 1e30f;
    r.q[0] = make_float4(__fsub_rn(x2, x1), __fsub_rn(y2, y1), x1, y1);
    r.q[1] = make_float4(__fsub_rn(x0, x2), __fsub_rn(y0, y2), x2, y2);
    r.q[2] = make_float4(__fsub_rn(x1, x0), __fsub_rn(y1, y0), x0, y0);
    r.q[3] = make_float4(zz0, zz1, zz2, inv_area);
    r.q[4] = make_float4(fminf(fminf(x0, x1), x2), fmaxf(fmaxf(x0, x1), x2),
                         fminf(fminf(y0, y1), y2), fmaxf(fmaxf(y0, y1), y2));
  }
  recs[i] = r;
}

// Each block: one 16x16 pixel tile x one span of CH_PER_SPLIT face chunks.
// Winner merged via 64-bit atomicMin on key = (f32bits(zp)<<32)|face_idx.
// zp>0 so fp32 bits are order-preserving; low bits give lowest-index tie-break
// (== jnp.argmin first-occurrence). zp is bitwise identical across blocks.
__global__ __launch_bounds__(256) void raster_kernel(
    const FaceRec* __restrict__ recs,
    unsigned long long* __restrict__ keybuf) {
  __shared__ float4 lds4[FCHUNK * 5];  // 20 KB
  int b  = blockIdx.z / NSPLIT;
  int sp = blockIdx.z % NSPLIT;
  int x = blockIdx.x * 16 + threadIdx.x;
  int y = blockIdx.y * 16 + threadIdx.y;
  float px = (float)x + 0.5f, py = (float)y + 0.5f;
  const float4* src_base = (const float4*)(recs + (size_t)b * FPAD);
  int tid = threadIdx.y * 16 + threadIdx.x;

  float best_zp = INFINITY;
  int best = -1;

  for (int ch = sp * CH_PER_SPLIT; ch < (sp + 1) * CH_PER_SPLIT; ++ch) {
    const float4* src = src_base + (size_t)ch * FCHUNK * 5;
    #pragma unroll
    for (int j = 0; j < 5; ++j) lds4[tid + j * 256] = src[tid + j * 256];
    __syncthreads();
    int base = ch * FCHUNK;
    for (int i = 0; i < FCHUNK; ++i) {
      float4 q4 = lds4[i * 5 + 4];
      if (px >= q4.x && px <= q4.y && py >= q4.z && py <= q4.w) {
        float4 q0 = lds4[i * 5 + 0];
        float4 q1 = lds4[i * 5 + 1];
        float4 q2 = lds4[i * 5 + 2];
        float4 q3 = lds4[i * 5 + 3];
        float w0 = __fsub_rn(__fmul_rn(q0.x, __fsub_rn(py, q0.w)),
                             __fmul_rn(q0.y, __fsub_rn(px, q0.z)));
        float w1 = __fsub_rn(__fmul_rn(q1.x, __fsub_rn(py, q1.w)),
                             __fmul_rn(q1.y, __fsub_rn(px, q1.z)));
        float w2 = __fsub_rn(__fmul_rn(q2.x, __fsub_rn(py, q2.w)),
                             __fmul_rn(q2.y, __fsub_rn(px, q2.z)));
        float b0 = __fmul_rn(w0, q3.w);
        float b1 = __fmul_rn(w1, q3.w);
        float b2 = __fmul_rn(w2, q3.w);
        if (b0 >= 0.0f && b1 >= 0.0f && b2 >= 0.0f) {
          float invz = __fadd_rn(__fadd_rn(b0 / q3.x, b1 / q3.y), b2 / q3.z);
          if (invz > EPSF) {
            float zp = 1.0f / invz;
            if (zp < best_zp) { best_zp = zp; best = base + i; }
          }
        }
      }
    }
    __syncthreads();
  }

  if (best >= 0) {
    unsigned long long key =
        ((unsigned long long)__float_as_uint(best_zp) << 32) | (unsigned int)best;
    atomicMin(&keybuf[(size_t)b * HW + (size_t)y * W_IMG + x], key);
  }
}

__global__ void shade_kernel(const unsigned long long* __restrict__ keybuf,
                             const FaceRec* __restrict__ recs,
                             const int* __restrict__ f,
                             const float* __restrict__ vc,
                             const float* __restrict__ bg,
                             float* __restrict__ out) {
  int p = blockIdx.x * blockDim.x + threadIdx.x;
  if (p >= NB * HW) return;
  int b = p / HW, pix = p - b * HW;
  int y = pix / W_IMG, x = pix - y * W_IMG;
  float px = (float)x + 0.5f, py = (float)y + 0.5f;
  unsigned long long key = keybuf[p];
  float o0, o1, o2;
  if (key != 0xFFFFFFFFFFFFFFFFULL) {
    int best = (int)(unsigned int)(key & 0xFFFFFFFFu);
    float zmin = __uint_as_float((unsigned int)(key >> 32));
    const float* q = (const float*)(recs + (size_t)b * FPAD + best);
    float w0 = __fsub_rn(__fmul_rn(q[0], __fsub_rn(py, q[3])),
                         __fmul_rn(q[1], __fsub_rn(px, q[2])));
    float w1 = __fsub_rn(__fmul_rn(q[4], __fsub_rn(py, q[7])),
                         __fmul_rn(q[5], __fsub_rn(px, q[6])));
    float w2 = __fsub_rn(__fmul_rn(q[8], __fsub_rn(py, q[11])),
                         __fmul_rn(q[9], __fsub_rn(px, q[10])));
    float ia = q[15];
    float b0 = __fmul_rn(w0, ia), b1 = __fmul_rn(w1, ia), b2 = __fmul_rn(w2, ia);
    float pc0 = b0 / q[12], pc1 = b1 / q[13], pc2 = b2 / q[14];
    int i0 = f[best * 3 + 0], i1 = f[best * 3 + 1], i2 = f[best * 3 + 2];
    const float* c0p = vc + (size_t)i0 * 3;
    const float* c1p = vc + (size_t)i1 * 3;
    const float* c2p = vc + (size_t)i2 * 3;
    o0 = __fmul_rn(__fadd_rn(__fadd_rn(__fmul_rn(pc0, c0p[0]), __fmul_rn(pc1, c1p[0])),
                             __fmul_rn(pc2, c2p[0])), zmin);
    o1 = __fmul_rn(__fadd_rn(__fadd_rn(__fmul_rn(pc0, c0p[1]), __fmul_rn(pc1, c1p[1])),
                             __fmul_rn(pc2, c2p[1])), zmin);
    o2 = __fmul_rn(__fadd_rn(__fadd_rn(__fmul_rn(pc0, c0p[2]), __fmul_rn(pc1, c1p[2])),
                             __fmul_rn(pc2, c2p[2])), zmin);
  } else {
    o0 = bg[0]; o1 = bg[1]; o2 = bg[2];
  }
  size_t o = (size_t)p * 3;
  out[o + 0] = o0;
  out[o + 1] = o1;
  out[o + 2] = o2;
}

extern "C" void kernel_launch(void* const* d_in, const int* in_sizes, int n_in,
                              void* d_out, int out_size, void* d_ws, size_t ws_size,
                              hipStream_t stream) {
  const float* v   = (const float*)d_in[0];
  const float* vc  = (const float*)d_in[1];
  const float* bg  = (const float*)d_in[2];
  const float* cf  = (const float*)d_in[3];
  const float* cc  = (const float*)d_in[4];
  const float* ct  = (const float*)d_in[5];
  const float* crt = (const float*)d_in[6];
  const int*   f   = (const int*)d_in[7];
  float* out = (float*)d_out;

  float4*  verts = (float4*)d_ws;                                 // 220,480 B
  FaceRec* recs  = (FaceRec*)((char*)d_ws + 262144);              // 2,211,840 B
  unsigned long long* keybuf =
      (unsigned long long*)((char*)d_ws + 262144 + 2211840);      // 802,816 B

  hipMemsetAsync(keybuf, 0xFF, (size_t)NB * HW * 8, stream);
  hipLaunchKernelGGL(proj_kernel, dim3((NB * NV + 255) / 256), dim3(256), 0, stream,
                     v, cf, cc, ct, crt, verts);
  hipLaunchKernelGGL(face_kernel, dim3(NB * FPAD / 256), dim3(256), 0, stream,
                     f, verts, recs);
  hipLaunchKernelGGL(raster_kernel, dim3(W_IMG / 16, H_IMG / 16, NB * NSPLIT),
                     dim3(16, 16), 0, stream, recs, keybuf);
  hipLaunchKernelGGL(shade_kernel, dim3((NB * HW + 255) / 256), dim3(256), 0, stream,
                     keybuf, recs, f, vc, bg, out);
}

// Round 5
// 748.159 us; speedup vs baseline: 4.5538x; 1.1740x over previous
//
#include <hip/hip_runtime.h>
#include <math.h>

#define H_IMG 224
#define W_IMG 224
#define HW (H_IMG * W_IMG)
#define EPSF 1e-8f
#define NV 6890
#define NF 13776
#define NB 2
#define FCHUNK 128
#define NCHUNK ((NF + FCHUNK - 1) / FCHUNK)   // 108
#define FPAD (NCHUNK * FCHUNK)                // 13824
#define NSPLIT 4
#define NBUCK 1024
#define CHDR_STRIDE 128
#define KEY_INIT 0x7F800000FFFFFFFFULL        // zp=+inf, idx=~0

// workspace byte offsets (256-aligned)
#define OFF_VERTS 0u                          // NB*NV*16      = 220,480
#define OFF_ZBU   220672u                     // NB*NF*4       = 110,208
#define OFF_ZBS   331008u                     // NB*FPAD*4     = 110,592
#define OFF_BBS   441600u                     // NB*FPAD*16    = 442,368
#define OFF_GMS   883968u                     // NB*FPAD*64    = 1,769,472
#define OFF_OIS   2653440u                    // NB*FPAD*4     = 110,592
#define OFF_INV   2764032u                    // NB*NF*4       = 110,208
#define OFF_CHDR  2874368u                    // NB*128*4      = 1,024
#define OFF_CNT   2875392u                    // NB*1024*4     = 8,192
#define OFF_OFFS  2883584u                    // NB*1024*4     = 8,192
#define OFF_KEY   2891776u                    // NB*HW*8       = 802,816  (end ~3.69 MB)

__global__ void proj_kernel(const float* __restrict__ v,
                            const float* __restrict__ cf,
                            const float* __restrict__ cc,
                            const float* __restrict__ ct,
                            const float* __restrict__ crt,
                            float4* __restrict__ verts) {
  int i = blockIdx.x * blockDim.x + threadIdx.x;
  if (i >= NB * NV) return;
  float r0 = crt[0], r1 = crt[1], r2 = crt[2];
  float ss = __fadd_rn(__fadd_rn(__fmul_rn(r0, r0), __fmul_rn(r1, r1)), __fmul_rn(r2, r2));
  float th = sqrtf(__fadd_rn(ss, 1e-12f));
  float kx = r0 / th, ky = r1 / th, kz = r2 / th;
  float c = cosf(th), s = sinf(th), oc = 1.0f - c;
  float R00 = c + oc * kx * kx,      R01 = oc * kx * ky - s * kz, R02 = oc * kx * kz + s * ky;
  float R10 = oc * ky * kx + s * kz, R11 = c + oc * ky * ky,      R12 = oc * ky * kz - s * kx;
  float R20 = oc * kz * kx - s * ky, R21 = oc * kz * ky + s * kx, R22 = c + oc * kz * kz;
  float x = v[i * 3 + 0], y = v[i * 3 + 1], z = v[i * 3 + 2];
  float xc = R00 * x + R01 * y + R02 * z + ct[0];
  float yc = R10 * x + R11 * y + R12 * z + ct[1];
  float zc = R20 * x + R21 * y + R22 * z + ct[2];
  float zs = fmaxf(zc, EPSF);
  float u = __fadd_rn(__fmul_rn(xc / zs, cf[0]), cc[0]);
  float w = __fadd_rn(__fmul_rn(yc / zs, cf[1]), cc[1]);
  verts[i] = make_float4(u, w, zc, 0.0f);
}

__global__ void init_kernel(unsigned long long* __restrict__ keybuf,
                            float* __restrict__ zbS, float4* __restrict__ bbS,
                            unsigned* __restrict__ chdr, unsigned* __restrict__ cnt) {
  int t = blockIdx.x * blockDim.x + threadIdx.x;
  if (t < NB * HW) keybuf[t] = KEY_INIT;
  if (t < NB * FPAD) {
    zbS[t] = INFINITY;
    bbS[t] = make_float4(1e30f, -1e30f, 1e30f, -1e30f);  // always-miss
  }
  if (t < NB * CHDR_STRIDE) chdr[t] = 0x7F800000u;       // +inf bits
  if (t < NB * NBUCK) cnt[t] = 0u;
}

// Depth lower-bound per face + bucket histogram.
// zb <= zp guaranteed: zp = 1/(sum b_i/z_i) >= minz/(1+serr), serr ~ 3*werr/|area|
// with werr bounded by ~5 ulps of the largest edge-function product term
// ((2M)*(M+256), M = max |coord|). Tight bound (slack 1e-3) only when
// 3*werr <= 5e-4*|area| (2x margin); else zb=0 => face never depth-culled.
__global__ void zb_kernel(const int* __restrict__ f, const float4* __restrict__ verts,
                          float* __restrict__ zbU, unsigned* __restrict__ cnt) {
  int i = blockIdx.x * blockDim.x + threadIdx.x;
  if (i >= NB * NF) return;
  int b = i / NF, fi = i - b * NF;
  int i0 = f[fi * 3 + 0], i1 = f[fi * 3 + 1], i2 = f[fi * 3 + 2];
  float4 p0 = verts[b * NV + i0], p1 = verts[b * NV + i1], p2 = verts[b * NV + i2];
  float area = __fsub_rn(__fmul_rn(__fsub_rn(p1.x, p0.x), __fsub_rn(p2.y, p0.y)),
                         __fmul_rn(__fsub_rn(p1.y, p0.y), __fsub_rn(p2.x, p0.x)));
  bool nz = fabsf(area) > EPSF;
  bool zv = (p0.z > EPSF) && (p1.z > EPSF) && (p2.z > EPSF);
  bool ok = nz && zv;
  float zb;
  if (!ok) {
    zb = 3e30f;  // invalid: can never produce a hit (inv_z <= EPS); sorts last
  } else {
    float minz = fminf(fminf(fmaxf(p0.z, EPSF), fmaxf(p1.z, EPSF)), fmaxf(p2.z, EPSF));
    float M = fmaxf(fmaxf(fmaxf(fabsf(p0.x), fabsf(p0.y)), fmaxf(fabsf(p1.x), fabsf(p1.y))),
                    fmaxf(fabsf(p2.x), fabsf(p2.y)));
    float werr = (2.0f * M) * (M + 256.0f) * 6e-7f;   // ~5 ulps of max product term
    bool tight = (3.0f * werr) <= (5e-4f * fabsf(area));
    zb = tight ? __fmul_rn(minz, 0.999f) : 0.0f;
  }
  zbU[i] = zb;
  int bucket = (int)fminf(fmaxf(zb * 256.0f, 0.0f), (float)(NBUCK - 1));
  atomicAdd(&cnt[b * NBUCK + bucket], 1u);
}

__global__ __launch_bounds__(1024) void scan_kernel(const unsigned* __restrict__ cnt,
                                                    unsigned* __restrict__ offs) {
  __shared__ unsigned s[NBUCK];
  int t = threadIdx.x;
  for (int b = 0; b < NB; ++b) {
    unsigned v = cnt[b * NBUCK + t];
    s[t] = v;
    __syncthreads();
    unsigned acc = v;
    for (int d = 1; d < NBUCK; d <<= 1) {
      unsigned add = (t >= d) ? s[t - d] : 0u;
      __syncthreads();
      acc += add;
      s[t] = acc;
      __syncthreads();
    }
    offs[b * NBUCK + t] = acc - v;  // exclusive
    __syncthreads();
  }
}

// Scatter into depth-sorted SoA. Record values are computed with the exact
// reference fp32 op sequence, so results are bit-identical regardless of the
// (non-deterministic) position a face lands at within its bucket.
__global__ void scatter_kernel(const int* __restrict__ f, const float4* __restrict__ verts,
                               const float* __restrict__ zbU, unsigned* __restrict__ offs,
                               float* __restrict__ zbS, float4* __restrict__ bbS,
                               float4* __restrict__ gmS, int* __restrict__ oiS,
                               int* __restrict__ inv, unsigned* __restrict__ chdr) {
  int i = blockIdx.x * blockDim.x + threadIdx.x;
  if (i >= NB * NF) return;
  int b = i / NF, fi = i - b * NF;
  float zb = zbU[i];
  int bucket = (int)fminf(fmaxf(zb * 256.0f, 0.0f), (float)(NBUCK - 1));
  unsigned pos = atomicAdd(&offs[b * NBUCK + bucket], 1u);
  int i0 = f[fi * 3 + 0], i1 = f[fi * 3 + 1], i2 = f[fi * 3 + 2];
  float4 p0 = verts[b * NV + i0], p1 = verts[b * NV + i1], p2 = verts[b * NV + i2];
  float x0 = p0.x, y0 = p0.y, z0 = p0.z;
  float x1 = p1.x, y1 = p1.y, z1 = p1.z;
  float x2 = p2.x, y2 = p2.y, z2 = p2.z;
  float area = __fsub_rn(__fmul_rn(__fsub_rn(x1, x0), __fsub_rn(y2, y0)),
                         __fmul_rn(__fsub_rn(y1, y0), __fsub_rn(x2, x0)));
  bool nz = fabsf(area) > EPSF;
  float inv_area = nz ? (1.0f / area) : 0.0f;
  bool zv = (z0 > EPSF) && (z1 > EPSF) && (z2 > EPSF);
  bool ok = nz && zv;
  float zz0 = ok ? fmaxf(z0, EPSF) : 1e30f;
  float zz1 = ok ? fmaxf(z1, EPSF) : 1e30f;
  float zz2 = ok ? fmaxf(z2, EPSF) : 1e30f;
  size_t sp_ = (size_t)b * FPAD + pos;
  zbS[sp_] = zb;
  bbS[sp_] = make_float4(fminf(fminf(x0, x1), x2), fmaxf(fmaxf(x0, x1), x2),
                         fminf(fminf(y0, y1), y2), fmaxf(fmaxf(y0, y1), y2));
  gmS[sp_ * 4 + 0] = make_float4(__fsub_rn(x2, x1), __fsub_rn(y2, y1), x1, y1);
  gmS[sp_ * 4 + 1] = make_float4(__fsub_rn(x0, x2), __fsub_rn(y0, y2), x2, y2);
  gmS[sp_ * 4 + 2] = make_float4(__fsub_rn(x1, x0), __fsub_rn(y1, y0), x0, y0);
  gmS[sp_ * 4 + 3] = make_float4(zz0, zz1, zz2, inv_area);
  oiS[sp_] = fi;
  inv[i] = (int)pos;
  atomicMin(&chdr[b * CHDR_STRIDE + (int)(pos / FCHUNK)], __float_as_uint(zb));
}

// One wave per 8x8 tile x NSPLIT interleaved front-to-back chunk subsequences.
// Winner = min over packed key (f32bits(zp)<<32)|orig_idx — commutative, and
// reproduces jnp.argmin's lowest-index tie-break. Skips are strictly
// conservative: drop a face only when zb > best_zp for ALL lanes.
__global__ void raster_kernel(const unsigned* __restrict__ chdr,
                              const float* __restrict__ zbS,
                              const float4* __restrict__ bbS,
                              const float4* __restrict__ gmS,
                              const int* __restrict__ oiS,
                              unsigned long long* __restrict__ keybuf) {
  int bz = blockIdx.z;
  int b = bz >> 2, sp = bz & (NSPLIT - 1);
  int x = blockIdx.x * 8 + (threadIdx.x & 7);
  int y = blockIdx.y * 8 + (threadIdx.x >> 3);
  float px = (float)x + 0.5f, py = (float)y + 0.5f;
  const unsigned* chdrB = chdr + b * CHDR_STRIDE;
  const float*  zbB = zbS + (size_t)b * FPAD;
  const float4* bbB = bbS + (size_t)b * FPAD;
  const float4* gmB = gmS + (size_t)b * FPAD * 4;
  const int*    oiB = oiS + (size_t)b * FPAD;

  unsigned long long bestKey = KEY_INIT;

  auto EVAL = [&](int fi) {
    float4 q4 = bbB[fi];
    if (px >= q4.x && px <= q4.y && py >= q4.z && py <= q4.w) {
      const float4* g = &gmB[(size_t)fi * 4];
      float4 q0 = g[0], q1 = g[1], q2 = g[2], q3 = g[3];
      float w0 = __fsub_rn(__fmul_rn(q0.x, __fsub_rn(py, q0.w)),
                           __fmul_rn(q0.y, __fsub_rn(px, q0.z)));
      float w1 = __fsub_rn(__fmul_rn(q1.x, __fsub_rn(py, q1.w)),
                           __fmul_rn(q1.y, __fsub_rn(px, q1.z)));
      float w2 = __fsub_rn(__fmul_rn(q2.x, __fsub_rn(py, q2.w)),
                           __fmul_rn(q2.y, __fsub_rn(px, q2.z)));
      float b0 = __fmul_rn(w0, q3.w);
      float b1 = __fmul_rn(w1, q3.w);
      float b2 = __fmul_rn(w2, q3.w);
      if (b0 >= 0.0f && b1 >= 0.0f && b2 >= 0.0f) {
        float invz = __fadd_rn(__fadd_rn(b0 / q3.x, b1 / q3.y), b2 / q3.z);
        if (invz > EPSF) {
          float zp = 1.0f / invz;
          unsigned long long key =
              ((unsigned long long)__float_as_uint(zp) << 32) | (unsigned)oiB[fi];
          if (key < bestKey) bestKey = key;
        }
      }
    }
  };

  for (int c = sp; c < NCHUNK; c += NSPLIT) {
    float czb = __uint_as_float(chdrB[c]);
    float bzp = __uint_as_float((unsigned)(bestKey >> 32));
    if (!__any(czb <= bzp)) continue;
    int base = c * FCHUNK;
    for (int i = 0; i < FCHUNK; i += 4) {
      float4 z4 = *(const float4*)&zbB[base + i];  // wave-uniform 16B broadcast load
      float bz2 = __uint_as_float((unsigned)(bestKey >> 32));
      bool a0 = z4.x <= bz2, a1 = z4.y <= bz2, a2 = z4.z <= bz2, a3 = z4.w <= bz2;
      if (!__any(a0 | a1 | a2 | a3)) continue;
      if (__any(a0)) EVAL(base + i + 0);
      if (__any(a1)) EVAL(base + i + 1);
      if (__any(a2)) EVAL(base + i + 2);
      if (__any(a3)) EVAL(base + i + 3);
    }
  }

  if (bestKey != KEY_INIT)
    atomicMin(&keybuf[(size_t)b * HW + (size_t)y * W_IMG + x], bestKey);
}

__global__ void shade_kernel(const unsigned long long* __restrict__ keybuf,
                             const float4* __restrict__ gmS,
                             const int* __restrict__ inv,
                             const int* __restrict__ f,
                             const float* __restrict__ vc,
                             const float* __restrict__ bg,
                             float* __restrict__ out) {
  int p = blockIdx.x * blockDim.x + threadIdx.x;
  if (p >= NB * HW) return;
  int b = p / HW, pix = p - b * HW;
  int y = pix / W_IMG, x = pix - y * W_IMG;
  float px = (float)x + 0.5f, py = (float)y + 0.5f;
  unsigned long long key = keybuf[p];
  float o0, o1, o2;
  if (key != KEY_INIT) {
    int best = (int)(unsigned)(key & 0xFFFFFFFFu);
    float zmin = __uint_as_float((unsigned)(key >> 32));
    int pos = inv[b * NF + best];
    const float4* g = &gmS[((size_t)b * FPAD + pos) * 4];
    float4 q0 = g[0], q1 = g[1], q2 = g[2], q3 = g[3];
    float w0 = __fsub_rn(__fmul_rn(q0.x, __fsub_rn(py, q0.w)),
                         __fmul_rn(q0.y, __fsub_rn(px, q0.z)));
    float w1 = __fsub_rn(__fmul_rn(q1.x, __fsub_rn(py, q1.w)),
                         __fmul_rn(q1.y, __fsub_rn(px, q1.z)));
    float w2 = __fsub_rn(__fmul_rn(q2.x, __fsub_rn(py, q2.w)),
                         __fmul_rn(q2.y, __fsub_rn(px, q2.z)));
    float b0 = __fmul_rn(w0, q3.w), b1 = __fmul_rn(w1, q3.w), b2 = __fmul_rn(w2, q3.w);
    float pc0 = b0 / q3.x, pc1 = b1 / q3.y, pc2 = b2 / q3.z;
    int i0 = f[best * 3 + 0], i1 = f[best * 3 + 1], i2 = f[best * 3 + 2];
    const float* c0p = vc + (size_t)i0 * 3;
    const float* c1p = vc + (size_t)i1 * 3;
    const float* c2p = vc + (size_t)i2 * 3;
    o0 = __fmul_rn(__fadd_rn(__fadd_rn(__fmul_rn(pc0, c0p[0]), __fmul_rn(pc1, c1p[0])),
                             __fmul_rn(pc2, c2p[0])), zmin);
    o1 = __fmul_rn(__fadd_rn(__fadd_rn(__fmul_rn(pc0, c0p[1]), __fmul_rn(pc1, c1p[1])),
                             __fmul_rn(pc2, c2p[1])), zmin);
    o2 = __fmul_rn(__fadd_rn(__fadd_rn(__fmul_rn(pc0, c0p[2]), __fmul_rn(pc1, c1p[2])),
                             __fmul_rn(pc2, c2p[2])), zmin);
  } else {
    o0 = bg[0]; o1 = bg[1]; o2 = bg[2];
  }
  size_t o = (size_t)p * 3;
  out[o + 0] = o0;
  out[o + 1] = o1;
  out[o + 2] = o2;
}

extern "C" void kernel_launch(void* const* d_in, const int* in_sizes, int n_in,
                              void* d_out, int out_size, void* d_ws, size_t ws_size,
                              hipStream_t stream) {
  const float* v   = (const float*)d_in[0];
  const float* vc  = (const float*)d_in[1];
  const float* bg  = (const float*)d_in[2];
  const float* cf  = (const float*)d_in[3];
  const float* cc  = (const float*)d_in[4];
  const float* ct  = (const float*)d_in[5];
  const float* crt = (const float*)d_in[6];
  const int*   f   = (const int*)d_in[7];
  float* out = (float*)d_out;
  char* ws = (char*)d_ws;

  float4*   verts = (float4*)(ws + OFF_VERTS);
  float*    zbU   = (float*)(ws + OFF_ZBU);
  float*    zbS   = (float*)(ws + OFF_ZBS);
  float4*   bbS   = (float4*)(ws + OFF_BBS);
  float4*   gmS   = (float4*)(ws + OFF_GMS);
  int*      oiS   = (int*)(ws + OFF_OIS);
  int*      inv   = (int*)(ws + OFF_INV);
  unsigned* chdr  = (unsigned*)(ws + OFF_CHDR);
  unsigned* cnt   = (unsigned*)(ws + OFF_CNT);
  unsigned* offs  = (unsigned*)(ws + OFF_OFFS);
  unsigned long long* keybuf = (unsigned long long*)(ws + OFF_KEY);

  hipLaunchKernelGGL(init_kernel, dim3((NB * HW + 255) / 256), dim3(256), 0, stream,
                     keybuf, zbS, bbS, chdr, cnt);
  hipLaunchKernelGGL(proj_kernel, dim3((NB * NV + 255) / 256), dim3(256), 0, stream,
                     v, cf, cc, ct, crt, verts);
  hipLaunchKernelGGL(zb_kernel, dim3((NB * NF + 255) / 256), dim3(256), 0, stream,
                     f, verts, zbU, cnt);
  hipLaunchKernelGGL(scan_kernel, dim3(1), dim3(1024), 0, stream, cnt, offs);
  hipLaunchKernelGGL(scatter_kernel, dim3((NB * NF + 255) / 256), dim3(256), 0, stream,
                     f, verts, zbU, offs, zbS, bbS, gmS, oiS, inv, chdr);
  hipLaunchKernelGGL(raster_kernel, dim3(W_IMG / 8, H_IMG / 8, NB * NSPLIT),
                     dim3(64), 0, stream, chdr, zbS, bbS, gmS, oiS, keybuf);
  hipLaunchKernelGGL(shade_kernel, dim3((NB * HW + 255) / 256), dim3(256), 0, stream,
                     keybuf, gmS, inv, f, vc, bg, out);
}

// Round 7
// 589.268 us; speedup vs baseline: 5.7817x; 1.2696x over previous
//
#include <hip/hip_runtime.h>
#include <math.h>

#define H_IMG 224
#define W_IMG 224
#define HW (H_IMG * W_IMG)
#define EPSF 1e-8f
#define NV 6890
#define NF 13776
#define NB 2
#define FCHUNK 128
#define NCHUNK ((NF + FCHUNK - 1) / FCHUNK)   // 108
#define FPAD (NCHUNK * FCHUNK)                // 13824
#define NBUCK 1024
#define CHDR_STRIDE 128
#define KEY_INIT 0x7F800000FFFFFFFFULL        // zp=+inf, idx=~0

// workspace byte offsets (256-aligned)
#define OFF_VERTS 0u                          // NB*NV*16      = 220,480
#define OFF_ZBU   220672u                     // NB*NF*4       = 110,208
#define OFF_ZBS   331008u                     // NB*FPAD*4     = 110,592
#define OFF_BBS   441600u                     // NB*FPAD*16    = 442,368
#define OFF_GMS   883968u                     // NB*FPAD*64    = 1,769,472
#define OFF_OIS   2653440u                    // NB*FPAD*4     = 110,592
#define OFF_INV   2764032u                    // NB*NF*4       = 110,208
#define OFF_CHDR  2874368u                    // NB*128*4      = 1,024
#define OFF_CNT   2875392u                    // NB*1024*4     = 8,192
#define OFF_OFFS  2883584u                    // NB*1024*4     = 8,192
#define OFF_KEY   2891776u                    // NB*HW*8       = 802,816  (end ~3.69 MB)

__device__ inline unsigned long long shfl_xor_u64(unsigned long long v, int m) {
  unsigned lo = (unsigned)v, hi = (unsigned)(v >> 32);
  lo = __shfl_xor(lo, m);
  hi = __shfl_xor(hi, m);
  return ((unsigned long long)hi << 32) | lo;
}

__global__ void proj_kernel(const float* __restrict__ v,
                            const float* __restrict__ cf,
                            const float* __restrict__ cc,
                            const float* __restrict__ ct,
                            const float* __restrict__ crt,
                            float4* __restrict__ verts) {
  int i = blockIdx.x * blockDim.x + threadIdx.x;
  if (i >= NB * NV) return;
  float r0 = crt[0], r1 = crt[1], r2 = crt[2];
  float ss = __fadd_rn(__fadd_rn(__fmul_rn(r0, r0), __fmul_rn(r1, r1)), __fmul_rn(r2, r2));
  float th = sqrtf(__fadd_rn(ss, 1e-12f));
  float kx = r0 / th, ky = r1 / th, kz = r2 / th;
  float c = cosf(th), s = sinf(th), oc = 1.0f - c;
  float R00 = c + oc * kx * kx,      R01 = oc * kx * ky - s * kz, R02 = oc * kx * kz + s * ky;
  float R10 = oc * ky * kx + s * kz, R11 = c + oc * ky * ky,      R12 = oc * ky * kz - s * kx;
  float R20 = oc * kz * kx - s * ky, R21 = oc * kz * ky + s * kx, R22 = c + oc * kz * kz;
  float x = v[i * 3 + 0], y = v[i * 3 + 1], z = v[i * 3 + 2];
  float xc = R00 * x + R01 * y + R02 * z + ct[0];
  float yc = R10 * x + R11 * y + R12 * z + ct[1];
  float zc = R20 * x + R21 * y + R22 * z + ct[2];
  float zs = fmaxf(zc, EPSF);
  float u = __fadd_rn(__fmul_rn(xc / zs, cf[0]), cc[0]);
  float w = __fadd_rn(__fmul_rn(yc / zs, cf[1]), cc[1]);
  verts[i] = make_float4(u, w, zc, 0.0f);
}

__global__ void init_kernel(unsigned long long* __restrict__ keybuf,
                            float* __restrict__ zbS, float4* __restrict__ bbS,
                            unsigned* __restrict__ chdr, unsigned* __restrict__ cnt) {
  int t = blockIdx.x * blockDim.x + threadIdx.x;
  if (t < NB * HW) keybuf[t] = KEY_INIT;
  if (t < NB * FPAD) {
    zbS[t] = 3e30f;                                      // pad: sorts last, prefilter-killable
    bbS[t] = make_float4(1e30f, -1e30f, 1e30f, -1e30f);  // always-miss
  }
  if (t < NB * CHDR_STRIDE) chdr[t] = 0x7F800000u;       // +inf bits
  if (t < NB * NBUCK) cnt[t] = 0u;
}

// Depth lower-bound per face + bucket histogram.
// zb <= zp guaranteed: zp = 1/(sum b_i/z_i) >= minz/(1+serr), serr ~ 3*werr/|area|
// with werr ~5 ulps of the largest edge-function product term. Tight bound
// (slack 1e-3) only when 3*werr <= 5e-4*|area|; else zb=0 (never depth-culled).
__global__ void zb_kernel(const int* __restrict__ f, const float4* __restrict__ verts,
                          float* __restrict__ zbU, unsigned* __restrict__ cnt) {
  int i = blockIdx.x * blockDim.x + threadIdx.x;
  if (i >= NB * NF) return;
  int b = i / NF, fi = i - b * NF;
  int i0 = f[fi * 3 + 0], i1 = f[fi * 3 + 1], i2 = f[fi * 3 + 2];
  float4 p0 = verts[b * NV + i0], p1 = verts[b * NV + i1], p2 = verts[b * NV + i2];
  float area = __fsub_rn(__fmul_rn(__fsub_rn(p1.x, p0.x), __fsub_rn(p2.y, p0.y)),
                         __fmul_rn(__fsub_rn(p1.y, p0.y), __fsub_rn(p2.x, p0.x)));
  bool nz = fabsf(area) > EPSF;
  bool zv = (p0.z > EPSF) && (p1.z > EPSF) && (p2.z > EPSF);
  bool ok = nz && zv;
  float zb;
  if (!ok) {
    zb = 3e30f;  // invalid: can never produce a hit (inv_z <= EPS); sorts last
  } else {
    float minz = fminf(fminf(fmaxf(p0.z, EPSF), fmaxf(p1.z, EPSF)), fmaxf(p2.z, EPSF));
    float M = fmaxf(fmaxf(fmaxf(fabsf(p0.x), fabsf(p0.y)), fmaxf(fabsf(p1.x), fabsf(p1.y))),
                    fmaxf(fabsf(p2.x), fabsf(p2.y)));
    float werr = (2.0f * M) * (M + 256.0f) * 6e-7f;
    bool tight = (3.0f * werr) <= (5e-4f * fabsf(area));
    zb = tight ? __fmul_rn(minz, 0.999f) : 0.0f;
  }
  zbU[i] = zb;
  int bucket = (int)fminf(fmaxf(zb * 256.0f, 0.0f), (float)(NBUCK - 1));
  atomicAdd(&cnt[b * NBUCK + bucket], 1u);
}

__global__ __launch_bounds__(1024) void scan_kernel(const unsigned* __restrict__ cnt,
                                                    unsigned* __restrict__ offs) {
  __shared__ unsigned s[NBUCK];
  int t = threadIdx.x;
  int b = blockIdx.x;  // one block per batch
  unsigned v = cnt[b * NBUCK + t];
  s[t] = v;
  __syncthreads();
  unsigned acc = v;
  for (int d = 1; d < NBUCK; d <<= 1) {
    unsigned add = (t >= d) ? s[t - d] : 0u;
    __syncthreads();
    acc += add;
    s[t] = acc;
    __syncthreads();
  }
  offs[b * NBUCK + t] = acc - v;  // exclusive
}

// Scatter into depth-sorted SoA. Record values use the exact reference fp32 op
// sequence -> bit-identical results regardless of within-bucket position.
__global__ void scatter_kernel(const int* __restrict__ f, const float4* __restrict__ verts,
                               const float* __restrict__ zbU, unsigned* __restrict__ offs,
                               float* __restrict__ zbS, float4* __restrict__ bbS,
                               float4* __restrict__ gmS, int* __restrict__ oiS,
                               int* __restrict__ inv, unsigned* __restrict__ chdr) {
  int i = blockIdx.x * blockDim.x + threadIdx.x;
  if (i >= NB * NF) return;
  int b = i / NF, fi = i - b * NF;
  float zb = zbU[i];
  int bucket = (int)fminf(fmaxf(zb * 256.0f, 0.0f), (float)(NBUCK - 1));
  unsigned pos = atomicAdd(&offs[b * NBUCK + bucket], 1u);
  int i0 = f[fi * 3 + 0], i1 = f[fi * 3 + 1], i2 = f[fi * 3 + 2];
  float4 p0 = verts[b * NV + i0], p1 = verts[b * NV + i1], p2 = verts[b * NV + i2];
  float x0 = p0.x, y0 = p0.y, z0 = p0.z;
  float x1 = p1.x, y1 = p1.y, z1 = p1.z;
  float x2 = p2.x, y2 = p2.y, z2 = p2.z;
  float area = __fsub_rn(__fmul_rn(__fsub_rn(x1, x0), __fsub_rn(y2, y0)),
                         __fmul_rn(__fsub_rn(y1, y0), __fsub_rn(x2, x0)));
  bool nz = fabsf(area) > EPSF;
  float inv_area = nz ? (1.0f / area) : 0.0f;
  bool zv = (z0 > EPSF) && (z1 > EPSF) && (z2 > EPSF);
  bool ok = nz && zv;
  float zz0 = ok ? fmaxf(z0, EPSF) : 1e30f;
  float zz1 = ok ? fmaxf(z1, EPSF) : 1e30f;
  float zz2 = ok ? fmaxf(z2, EPSF) : 1e30f;
  size_t sp_ = (size_t)b * FPAD + pos;
  zbS[sp_] = zb;
  bbS[sp_] = make_float4(fminf(fminf(x0, x1), x2), fmaxf(fmaxf(x0, x1), x2),
                         fminf(fminf(y0, y1), y2), fmaxf(fmaxf(y0, y1), y2));
  gmS[sp_ * 4 + 0] = make_float4(__fsub_rn(x2, x1), __fsub_rn(y2, y1), x1, y1);
  gmS[sp_ * 4 + 1] = make_float4(__fsub_rn(x0, x2), __fsub_rn(y0, y2), x2, y2);
  gmS[sp_ * 4 + 2] = make_float4(__fsub_rn(x1, x0), __fsub_rn(y1, y0), x0, y0);
  gmS[sp_ * 4 + 3] = make_float4(zz0, zz1, zz2, inv_area);
  oiS[sp_] = fi;
  inv[i] = (int)pos;
  atomicMin(&chdr[b * CHDR_STRIDE + (int)(pos / FCHUNK)], __float_as_uint(zb));
}

// Suffix-min over chunk headers: chdr[c] := min over chunks >= c. Makes the
// raster break unconditionally conservative (within-bucket order and the
// clamped top bucket make raw per-chunk minima NON-monotone). uint min is
// order-preserving for nonnegative floats.
__global__ __launch_bounds__(CHDR_STRIDE) void suffix_kernel(unsigned* __restrict__ chdr) {
  __shared__ unsigned s[CHDR_STRIDE];
  int t = threadIdx.x, b = blockIdx.x;
  s[t] = chdr[b * CHDR_STRIDE + t];
  __syncthreads();
  for (int d = 1; d < CHDR_STRIDE; d <<= 1) {
    unsigned v = (t + d < CHDR_STRIDE) ? s[t + d] : 0x7F800000u;
    __syncthreads();
    s[t] = (v < s[t]) ? v : s[t];
    __syncthreads();
  }
  chdr[b * CHDR_STRIDE + t] = s[t];
}

// Wave = 16 pixels (4x4 tile) x 4 face-slots (slot = lane&3, pixel = lane>>2).
// Per 4-face group: lane loads its slot's zb (coalesced), tests vs its pixel's
// combined best (shfl-min across slots); passing lanes fully evaluate 4
// distinct faces concurrently. chdr[c] = suffix min zb over chunks >= c ->
// first all-lane failure proves nothing later can win -> break. All skips
// strictly conservative; winner = commutative min of (zp_bits<<32)|orig_idx.
__global__ __launch_bounds__(64) void raster_kernel(
    const unsigned* __restrict__ chdr,
    const float* __restrict__ zbS,
    const float4* __restrict__ bbS,
    const float4* __restrict__ gmS,
    const int* __restrict__ oiS,
    unsigned long long* __restrict__ keybuf) {
  int b = blockIdx.z;
  int lane = threadIdx.x;
  int slot = lane & 3;
  int p = lane >> 2;                       // 0..15
  int x = blockIdx.x * 4 + (p & 3);
  int y = blockIdx.y * 4 + (p >> 2);
  float px = (float)x + 0.5f, py = (float)y + 0.5f;
  const unsigned* chdrB = chdr + b * CHDR_STRIDE;
  const float*  zbB = zbS + (size_t)b * FPAD;
  const float4* bbB = bbS + (size_t)b * FPAD;
  const float4* gmB = gmS + (size_t)b * FPAD * 4;
  const int*    oiB = oiS + (size_t)b * FPAD;

  unsigned long long bestKey = KEY_INIT;

  for (int c = 0; c < NCHUNK; ++c) {
    float bz = __uint_as_float((unsigned)(bestKey >> 32));
    float comb = fminf(bz, __shfl_xor(bz, 1));
    comb = fminf(comb, __shfl_xor(comb, 2));
    float czb = __uint_as_float(chdrB[c]);   // suffix min: bound for ALL chunks >= c
    if (!__any(czb <= comb)) break;
    int base = c * FCHUNK;
    for (int g = 0; g < FCHUNK; g += 4) {
      float zb_s = zbB[base + g + slot];
      float bz2 = __uint_as_float((unsigned)(bestKey >> 32));
      float comb2 = fminf(bz2, __shfl_xor(bz2, 1));
      comb2 = fminf(comb2, __shfl_xor(comb2, 2));
      bool act = (zb_s <= comb2);
      if (!__any(act)) continue;           // per-face test, no ordering assumption
      if (act) {
        int fi = base + g + slot;
        float4 q4 = bbB[fi];
        if (px >= q4.x && px <= q4.y && py >= q4.z && py <= q4.w) {
          const float4* gm = &gmB[(size_t)fi * 4];
          float4 q0 = gm[0], q1 = gm[1], q2 = gm[2], q3 = gm[3];
          float w0 = __fsub_rn(__fmul_rn(q0.x, __fsub_rn(py, q0.w)),
                               __fmul_rn(q0.y, __fsub_rn(px, q0.z)));
          float w1 = __fsub_rn(__fmul_rn(q1.x, __fsub_rn(py, q1.w)),
                               __fmul_rn(q1.y, __fsub_rn(px, q1.z)));
          float w2 = __fsub_rn(__fmul_rn(q2.x, __fsub_rn(py, q2.w)),
                               __fmul_rn(q2.y, __fsub_rn(px, q2.z)));
          float b0 = __fmul_rn(w0, q3.w);
          float b1 = __fmul_rn(w1, q3.w);
          float b2 = __fmul_rn(w2, q3.w);
          if (b0 >= 0.0f && b1 >= 0.0f && b2 >= 0.0f) {
            float invz = __fadd_rn(__fadd_rn(b0 / q3.x, b1 / q3.y), b2 / q3.z);
            if (invz > EPSF) {
              float zp = 1.0f / invz;
              unsigned long long key =
                  ((unsigned long long)__float_as_uint(zp) << 32) | (unsigned)oiB[fi];
              if (key < bestKey) bestKey = key;
            }
          }
        }
      }
    }
  }

  // merge slots within each pixel quad
  unsigned long long o = shfl_xor_u64(bestKey, 1);
  if (o < bestKey) bestKey = o;
  o = shfl_xor_u64(bestKey, 2);
  if (o < bestKey) bestKey = o;
  if (slot == 0 && bestKey != KEY_INIT)
    atomicMin(&keybuf[(size_t)b * HW + (size_t)y * W_IMG + x], bestKey);
}

__global__ void shade_kernel(const unsigned long long* __restrict__ keybuf,
                             const float4* __restrict__ gmS,
                             const int* __restrict__ inv,
                             const int* __restrict__ f,
                             const float* __restrict__ vc,
                             const float* __restrict__ bg,
                             float* __restrict__ out) {
  int p = blockIdx.x * blockDim.x + threadIdx.x;
  if (p >= NB * HW) return;
  int b = p / HW, pix = p - b * HW;
  int y = pix / W_IMG, x = pix - y * W_IMG;
  float px = (float)x + 0.5f, py = (float)y + 0.5f;
  unsigned long long key = keybuf[p];
  float o0, o1, o2;
  if (key != KEY_INIT) {
    int best = (int)(unsigned)(key & 0xFFFFFFFFu);
    float zmin = __uint_as_float((unsigned)(key >> 32));
    int pos = inv[b * NF + best];
    const float4* g = &gmS[((size_t)b * FPAD + pos) * 4];
    float4 q0 = g[0], q1 = g[1], q2 = g[2], q3 = g[3];
    float w0 = __fsub_rn(__fmul_rn(q0.x, __fsub_rn(py, q0.w)),
                         __fmul_rn(q0.y, __fsub_rn(px, q0.z)));
    float w1 = __fsub_rn(__fmul_rn(q1.x, __fsub_rn(py, q1.w)),
                         __fmul_rn(q1.y, __fsub_rn(px, q1.z)));
    float w2 = __fsub_rn(__fmul_rn(q2.x, __fsub_rn(py, q2.w)),
                         __fmul_rn(q2.y, __fsub_rn(px, q2.z)));
    float b0 = __fmul_rn(w0, q3.w), b1 = __fmul_rn(w1, q3.w), b2 = __fmul_rn(w2, q3.w);
    float pc0 = b0 / q3.x, pc1 = b1 / q3.y, pc2 = b2 / q3.z;
    int i0 = f[best * 3 + 0], i1 = f[best * 3 + 1], i2 = f[best * 3 + 2];
    const float* c0p = vc + (size_t)i0 * 3;
    const float* c1p = vc + (size_t)i1 * 3;
    const float* c2p = vc + (size_t)i2 * 3;
    o0 = __fmul_rn(__fadd_rn(__fadd_rn(__fmul_rn(pc0, c0p[0]), __fmul_rn(pc1, c1p[0])),
                             __fmul_rn(pc2, c2p[0])), zmin);
    o1 = __fmul_rn(__fadd_rn(__fadd_rn(__fmul_rn(pc0, c0p[1]), __fmul_rn(pc1, c1p[1])),
                             __fmul_rn(pc2, c2p[1])), zmin);
    o2 = __fmul_rn(__fadd_rn(__fadd_rn(__fmul_rn(pc0, c0p[2]), __fmul_rn(pc1, c1p[2])),
                             __fmul_rn(pc2, c2p[2])), zmin);
  } else {
    o0 = bg[0]; o1 = bg[1]; o2 = bg[2];
  }
  size_t o = (size_t)p * 3;
  out[o + 0] = o0;
  out[o + 1] = o1;
  out[o + 2] = o2;
}

extern "C" void kernel_launch(void* const* d_in, const int* in_sizes, int n_in,
                              void* d_out, int out_size, void* d_ws, size_t ws_size,
                              hipStream_t stream) {
  const float* v   = (const float*)d_in[0];
  const float* vc  = (const float*)d_in[1];
  const float* bg  = (const float*)d_in[2];
  const float* cf  = (const float*)d_in[3];
  const float* cc  = (const float*)d_in[4];
  const float* ct  = (const float*)d_in[5];
  const float* crt = (const float*)d_in[6];
  const int*   f   = (const int*)d_in[7];
  float* out = (float*)d_out;
  char* ws = (char*)d_ws;

  float4*   verts = (float4*)(ws + OFF_VERTS);
  float*    zbU   = (float*)(ws + OFF_ZBU);
  float*    zbS   = (float*)(ws + OFF_ZBS);
  float4*   bbS   = (float4*)(ws + OFF_BBS);
  float4*   gmS   = (float4*)(ws + OFF_GMS);
  int*      oiS   = (int*)(ws + OFF_OIS);
  int*      inv   = (int*)(ws + OFF_INV);
  unsigned* chdr  = (unsigned*)(ws + OFF_CHDR);
  unsigned* cnt   = (unsigned*)(ws + OFF_CNT);
  unsigned* offs  = (unsigned*)(ws + OFF_OFFS);
  unsigned long long* keybuf = (unsigned long long*)(ws + OFF_KEY);

  hipLaunchKernelGGL(init_kernel, dim3((NB * HW + 255) / 256), dim3(256), 0, stream,
                     keybuf, zbS, bbS, chdr, cnt);
  hipLaunchKernelGGL(proj_kernel, dim3((NB * NV + 255) / 256), dim3(256), 0, stream,
                     v, cf, cc, ct, crt, verts);
  hipLaunchKernelGGL(zb_kernel, dim3((NB * NF + 255) / 256), dim3(256), 0, stream,
                     f, verts, zbU, cnt);
  hipLaunchKernelGGL(scan_kernel, dim3(NB), dim3(1024), 0, stream, cnt, offs);
  hipLaunchKernelGGL(scatter_kernel, dim3((NB * NF + 255) / 256), dim3(256), 0, stream,
                     f, verts, zbU, offs, zbS, bbS, gmS, oiS, inv, chdr);
  hipLaunchKernelGGL(suffix_kernel, dim3(NB), dim3(CHDR_STRIDE), 0, stream, chdr);
  hipLaunchKernelGGL(raster_kernel, dim3(W_IMG / 4, H_IMG / 4, NB),
                     dim3(64), 0, stream, chdr, zbS, bbS, gmS, oiS, keybuf);
  hipLaunchKernelGGL(shade_kernel, dim3((NB * HW + 255) / 256), dim3(256), 0, stream,
                     keybuf, gmS, inv, f, vc, bg, out);
}

// Round 9
// 557.138 us; speedup vs baseline: 6.1151x; 1.0577x over previous
//
#include <hip/hip_runtime.h>
#include <math.h>

#define H_IMG 224
#define W_IMG 224
#define HW (H_IMG * W_IMG)
#define EPSF 1e-8f
#define NV 6890
#define NF 13776
#define NB 2
#define FCHUNK 128
#define NCHUNK ((NF + FCHUNK - 1) / FCHUNK)   // 108
#define FPAD (NCHUNK * FCHUNK)                // 13824
#define NBUCK 1024
#define CHDR_STRIDE 128
#define KEY_INIT 0x7F800000FFFFFFFFULL        // zp=+inf, idx=~0

// workspace byte offsets (256-aligned)
#define OFF_VERTS 0u                          // NB*NV*16      = 220,480
#define OFF_ZBU   220672u                     // NB*NF*4       = 110,208
#define OFF_ZBS   331008u                     // NB*FPAD*4     = 110,592
#define OFF_BBS   441600u                     // NB*FPAD*16    = 442,368
#define OFF_GMS   883968u                     // NB*FPAD*64    = 1,769,472
#define OFF_OIS   2653440u                    // NB*FPAD*4     = 110,592
#define OFF_INV   2764032u                    // NB*NF*4       = 110,208
#define OFF_CHDR  2874368u                    // NB*128*4      = 1,024
#define OFF_CNT   2875392u                    // NB*1024*4     = 8,192
#define OFF_OFFS  2883584u                    // NB*1024*4     = 8,192
#define OFF_KEY   2891776u                    // NB*HW*8       = 802,816  (end ~3.69 MB)

__device__ inline unsigned long long shfl_xor_u64(unsigned long long v, int m) {
  unsigned lo = (unsigned)v, hi = (unsigned)(v >> 32);
  lo = __shfl_xor(lo, m);
  hi = __shfl_xor(hi, m);
  return ((unsigned long long)hi << 32) | lo;
}

__global__ void proj_kernel(const float* __restrict__ v,
                            const float* __restrict__ cf,
                            const float* __restrict__ cc,
                            const float* __restrict__ ct,
                            const float* __restrict__ crt,
                            float4* __restrict__ verts) {
  int i = blockIdx.x * blockDim.x + threadIdx.x;
  if (i >= NB * NV) return;
  float r0 = crt[0], r1 = crt[1], r2 = crt[2];
  float ss = __fadd_rn(__fadd_rn(__fmul_rn(r0, r0), __fmul_rn(r1, r1)), __fmul_rn(r2, r2));
  float th = sqrtf(__fadd_rn(ss, 1e-12f));
  float kx = r0 / th, ky = r1 / th, kz = r2 / th;
  float c = cosf(th), s = sinf(th), oc = 1.0f - c;
  float R00 = c + oc * kx * kx,      R01 = oc * kx * ky - s * kz, R02 = oc * kx * kz + s * ky;
  float R10 = oc * ky * kx + s * kz, R11 = c + oc * ky * ky,      R12 = oc * ky * kz - s * kx;
  float R20 = oc * kz * kx - s * ky, R21 = oc * kz * ky + s * kx, R22 = c + oc * kz * kz;
  float x = v[i * 3 + 0], y = v[i * 3 + 1], z = v[i * 3 + 2];
  float xc = R00 * x + R01 * y + R02 * z + ct[0];
  float yc = R10 * x + R11 * y + R12 * z + ct[1];
  float zc = R20 * x + R21 * y + R22 * z + ct[2];
  float zs = fmaxf(zc, EPSF);
  float u = __fadd_rn(__fmul_rn(xc / zs, cf[0]), cc[0]);
  float w = __fadd_rn(__fmul_rn(yc / zs, cf[1]), cc[1]);
  verts[i] = make_float4(u, w, zc, 0.0f);
}

__global__ void init_kernel(unsigned long long* __restrict__ keybuf,
                            float* __restrict__ zbS, float4* __restrict__ bbS,
                            unsigned* __restrict__ chdr, unsigned* __restrict__ cnt) {
  int t = blockIdx.x * blockDim.x + threadIdx.x;
  if (t < NB * HW) keybuf[t] = KEY_INIT;
  if (t < NB * FPAD) {
    zbS[t] = 3e30f;                                      // pad: sorts last, prefilter-killable
    bbS[t] = make_float4(1e30f, -1e30f, 1e30f, -1e30f);  // always-miss
  }
  if (t < NB * CHDR_STRIDE) chdr[t] = 0x7F800000u;       // +inf bits
  if (t < NB * NBUCK) cnt[t] = 0u;
}

// Depth lower-bound per face + bucket histogram.
// zb <= zp guaranteed: zp = 1/(sum b_i/z_i) >= minz/(1+serr), serr ~ 3*werr/|area|
// with werr ~5 ulps of the largest edge-function product term. Tight bound
// (slack 1e-3) only when 3*werr <= 5e-4*|area|; else zb=0 (never depth-culled).
__global__ void zb_kernel(const int* __restrict__ f, const float4* __restrict__ verts,
                          float* __restrict__ zbU, unsigned* __restrict__ cnt) {
  int i = blockIdx.x * blockDim.x + threadIdx.x;
  if (i >= NB * NF) return;
  int b = i / NF, fi = i - b * NF;
  int i0 = f[fi * 3 + 0], i1 = f[fi * 3 + 1], i2 = f[fi * 3 + 2];
  float4 p0 = verts[b * NV + i0], p1 = verts[b * NV + i1], p2 = verts[b * NV + i2];
  float area = __fsub_rn(__fmul_rn(__fsub_rn(p1.x, p0.x), __fsub_rn(p2.y, p0.y)),
                         __fmul_rn(__fsub_rn(p1.y, p0.y), __fsub_rn(p2.x, p0.x)));
  bool nz = fabsf(area) > EPSF;
  bool zv = (p0.z > EPSF) && (p1.z > EPSF) && (p2.z > EPSF);
  bool ok = nz && zv;
  float zb;
  if (!ok) {
    zb = 3e30f;  // invalid: can never produce a hit (inv_z <= EPS); sorts last
  } else {
    float minz = fminf(fminf(fmaxf(p0.z, EPSF), fmaxf(p1.z, EPSF)), fmaxf(p2.z, EPSF));
    float M = fmaxf(fmaxf(fmaxf(fabsf(p0.x), fabsf(p0.y)), fmaxf(fabsf(p1.x), fabsf(p1.y))),
                    fmaxf(fabsf(p2.x), fabsf(p2.y)));
    float werr = (2.0f * M) * (M + 256.0f) * 6e-7f;
    bool tight = (3.0f * werr) <= (5e-4f * fabsf(area));
    zb = tight ? __fmul_rn(minz, 0.999f) : 0.0f;
  }
  zbU[i] = zb;
  int bucket = (int)fminf(fmaxf(zb * 256.0f, 0.0f), (float)(NBUCK - 1));
  atomicAdd(&cnt[b * NBUCK + bucket], 1u);
}

__global__ __launch_bounds__(1024) void scan_kernel(const unsigned* __restrict__ cnt,
                                                    unsigned* __restrict__ offs) {
  __shared__ unsigned s[NBUCK];
  int t = threadIdx.x;
  int b = blockIdx.x;  // one block per batch
  unsigned v = cnt[b * NBUCK + t];
  s[t] = v;
  __syncthreads();
  unsigned acc = v;
  for (int d = 1; d < NBUCK; d <<= 1) {
    unsigned add = (t >= d) ? s[t - d] : 0u;
    __syncthreads();
    acc += add;
    s[t] = acc;
    __syncthreads();
  }
  offs[b * NBUCK + t] = acc - v;  // exclusive
}

// Scatter into depth-sorted SoA. Record values use the exact reference fp32 op
// sequence -> bit-identical results regardless of within-bucket position.
__global__ void scatter_kernel(const int* __restrict__ f, const float4* __restrict__ verts,
                               const float* __restrict__ zbU, unsigned* __restrict__ offs,
                               float* __restrict__ zbS, float4* __restrict__ bbS,
                               float4* __restrict__ gmS, int* __restrict__ oiS,
                               int* __restrict__ inv, unsigned* __restrict__ chdr) {
  int i = blockIdx.x * blockDim.x + threadIdx.x;
  if (i >= NB * NF) return;
  int b = i / NF, fi = i - b * NF;
  float zb = zbU[i];
  int bucket = (int)fminf(fmaxf(zb * 256.0f, 0.0f), (float)(NBUCK - 1));
  unsigned pos = atomicAdd(&offs[b * NBUCK + bucket], 1u);
  int i0 = f[fi * 3 + 0], i1 = f[fi * 3 + 1], i2 = f[fi * 3 + 2];
  float4 p0 = verts[b * NV + i0], p1 = verts[b * NV + i1], p2 = verts[b * NV + i2];
  float x0 = p0.x, y0 = p0.y, z0 = p0.z;
  float x1 = p1.x, y1 = p1.y, z1 = p1.z;
  float x2 = p2.x, y2 = p2.y, z2 = p2.z;
  float area = __fsub_rn(__fmul_rn(__fsub_rn(x1, x0), __fsub_rn(y2, y0)),
                         __fmul_rn(__fsub_rn(y1, y0), __fsub_rn(x2, x0)));
  bool nz = fabsf(area) > EPSF;
  float inv_area = nz ? (1.0f / area) : 0.0f;
  bool zv = (z0 > EPSF) && (z1 > EPSF) && (z2 > EPSF);
  bool ok = nz && zv;
  float zz0 = ok ? fmaxf(z0, EPSF) : 1e30f;
  float zz1 = ok ? fmaxf(z1, EPSF) : 1e30f;
  float zz2 = ok ? fmaxf(z2, EPSF) : 1e30f;
  size_t sp_ = (size_t)b * FPAD + pos;
  zbS[sp_] = zb;
  bbS[sp_] = make_float4(fminf(fminf(x0, x1), x2), fmaxf(fmaxf(x0, x1), x2),
                         fminf(fminf(y0, y1), y2), fmaxf(fmaxf(y0, y1), y2));
  gmS[sp_ * 4 + 0] = make_float4(__fsub_rn(x2, x1), __fsub_rn(y2, y1), x1, y1);
  gmS[sp_ * 4 + 1] = make_float4(__fsub_rn(x0, x2), __fsub_rn(y0, y2), x2, y2);
  gmS[sp_ * 4 + 2] = make_float4(__fsub_rn(x1, x0), __fsub_rn(y1, y0), x0, y0);
  gmS[sp_ * 4 + 3] = make_float4(zz0, zz1, zz2, inv_area);
  oiS[sp_] = fi;
  inv[i] = (int)pos;
  atomicMin(&chdr[b * CHDR_STRIDE + (int)(pos / FCHUNK)], __float_as_uint(zb));
}

// Suffix-min over chunk headers: chdr[c] := min over chunks >= c (uint min is
// order-preserving for nonnegative floats) -> raster break is conservative.
__global__ __launch_bounds__(CHDR_STRIDE) void suffix_kernel(unsigned* __restrict__ chdr) {
  __shared__ unsigned s[CHDR_STRIDE];
  int t = threadIdx.x, b = blockIdx.x;
  s[t] = chdr[b * CHDR_STRIDE + t];
  __syncthreads();
  for (int d = 1; d < CHDR_STRIDE; d <<= 1) {
    unsigned v = (t + d < CHDR_STRIDE) ? s[t + d] : 0x7F800000u;
    __syncthreads();
    s[t] = (v < s[t]) ? v : s[t];
    __syncthreads();
  }
  chdr[b * CHDR_STRIDE + t] = s[t];
}

// Block = 256 threads = 4 independent waves; each wave owns a 4x4 pixel tile
// (16 pixels x 4 face-slots). Prefilter is ballot-batched: per 64-face half-
// chunk each lane loads ONE distinct zb (coalesced, single load-latency
// exposure), compares vs wave-wide combMax (max over pixels of per-pixel best
// zp — conservative for every pixel), one __ballot -> 64-face candidate mask.
// Only set nibbles are evaluated (4 faces x 16 pixels concurrently).
// chdr[c] = suffix min -> first all-pixel failure proves nothing later wins.
// Winner = commutative min of (zp_bits<<32)|orig_idx; bit-exact ref math.
__global__ __launch_bounds__(256) void raster_kernel(
    const unsigned* __restrict__ chdr,
    const float* __restrict__ zbS,
    const float4* __restrict__ bbS,
    const float4* __restrict__ gmS,
    const int* __restrict__ oiS,
    unsigned long long* __restrict__ keybuf) {
  int b = blockIdx.z;
  int w = threadIdx.x >> 6;                // wave 0..3 -> 2x2 tile grid
  int lane = threadIdx.x & 63;
  int slot = lane & 3;
  int p = lane >> 2;                       // 0..15
  int x = (blockIdx.x * 2 + (w & 1)) * 4 + (p & 3);
  int y = (blockIdx.y * 2 + (w >> 1)) * 4 + (p >> 2);
  float px = (float)x + 0.5f, py = (float)y + 0.5f;
  const unsigned* chdrB = chdr + b * CHDR_STRIDE;
  const float*  zbB = zbS + (size_t)b * FPAD;
  const float4* bbB = bbS + (size_t)b * FPAD;
  const float4* gmB = gmS + (size_t)b * FPAD * 4;
  const int*    oiB = oiS + (size_t)b * FPAD;

  unsigned long long bestKey = KEY_INIT;

  for (int c = 0; c < NCHUNK; ++c) {
    float bz = __uint_as_float((unsigned)(bestKey >> 32));
    float comb = fminf(bz, __shfl_xor(bz, 1));        // min over 4 slots = pixel best
    comb = fminf(comb, __shfl_xor(comb, 2));
    float czb = __uint_as_float(chdrB[c]);            // suffix min over chunks >= c
    if (!__any(czb <= comb)) break;
    float combMax = fmaxf(comb, __shfl_xor(comb, 4)); // max over 16 pixels
    combMax = fmaxf(combMax, __shfl_xor(combMax, 8));
    combMax = fmaxf(combMax, __shfl_xor(combMax, 16));
    combMax = fmaxf(combMax, __shfl_xor(combMax, 32));
    int base = c * FCHUNK;
    #pragma unroll
    for (int h = 0; h < FCHUNK / 64; ++h) {
      int fbase = base + h * 64;
      float zb_lane = zbB[fbase + lane];              // 1 coalesced load / 64 faces
      unsigned long long m = __ballot(zb_lane <= combMax);
      unsigned long long mm = m;
      while (mm) {
        int bit = __builtin_ctzll(mm);
        int g = bit & ~3;                             // nibble = 4-face group
        mm &= ~(0xFULL << g);
        if ((m >> (g + slot)) & 1) {
          int fi = fbase + g + slot;
          float4 q4 = bbB[fi];
          if (px >= q4.x && px <= q4.y && py >= q4.z && py <= q4.w) {
            const float4* gm = &gmB[(size_t)fi * 4];
            float4 q0 = gm[0], q1 = gm[1], q2 = gm[2], q3 = gm[3];
            float w0 = __fsub_rn(__fmul_rn(q0.x, __fsub_rn(py, q0.w)),
                                 __fmul_rn(q0.y, __fsub_rn(px, q0.z)));
            float w1 = __fsub_rn(__fmul_rn(q1.x, __fsub_rn(py, q1.w)),
                                 __fmul_rn(q1.y, __fsub_rn(px, q1.z)));
            float w2 = __fsub_rn(__fmul_rn(q2.x, __fsub_rn(py, q2.w)),
                                 __fmul_rn(q2.y, __fsub_rn(px, q2.z)));
            float b0 = __fmul_rn(w0, q3.w);
            float b1 = __fmul_rn(w1, q3.w);
            float b2 = __fmul_rn(w2, q3.w);
            if (b0 >= 0.0f && b1 >= 0.0f && b2 >= 0.0f) {
              float invz = __fadd_rn(__fadd_rn(b0 / q3.x, b1 / q3.y), b2 / q3.z);
              if (invz > EPSF) {
                float zp = 1.0f / invz;
                unsigned long long key =
                    ((unsigned long long)__float_as_uint(zp) << 32) | (unsigned)oiB[fi];
                if (key < bestKey) bestKey = key;
              }
            }
          }
        }
      }
    }
  }

  // merge slots within each pixel quad
  unsigned long long o = shfl_xor_u64(bestKey, 1);
  if (o < bestKey) bestKey = o;
  o = shfl_xor_u64(bestKey, 2);
  if (o < bestKey) bestKey = o;
  if (slot == 0 && bestKey != KEY_INIT)
    atomicMin(&keybuf[(size_t)b * HW + (size_t)y * W_IMG + x], bestKey);
}

__global__ void shade_kernel(const unsigned long long* __restrict__ keybuf,
                             const float4* __restrict__ gmS,
                             const int* __restrict__ inv,
                             const int* __restrict__ f,
                             const float* __restrict__ vc,
                             const float* __restrict__ bg,
                             float* __restrict__ out) {
  int p = blockIdx.x * blockDim.x + threadIdx.x;
  if (p >= NB * HW) return;
  int b = p / HW, pix = p - b * HW;
  int y = pix / W_IMG, x = pix - y * W_IMG;
  float px = (float)x + 0.5f, py = (float)y + 0.5f;
  unsigned long long key = keybuf[p];
  float o0, o1, o2;
  if (key != KEY_INIT) {
    int best = (int)(unsigned)(key & 0xFFFFFFFFu);
    float zmin = __uint_as_float((unsigned)(key >> 32));
    int pos = inv[b * NF + best];
    const float4* g = &gmS[((size_t)b * FPAD + pos) * 4];
    float4 q0 = g[0], q1 = g[1], q2 = g[2], q3 = g[3];
    float w0 = __fsub_rn(__fmul_rn(q0.x, __fsub_rn(py, q0.w)),
                         __fmul_rn(q0.y, __fsub_rn(px, q0.z)));
    float w1 = __fsub_rn(__fmul_rn(q1.x, __fsub_rn(py, q1.w)),
                         __fmul_rn(q1.y, __fsub_rn(px, q1.z)));
    float w2 = __fsub_rn(__fmul_rn(q2.x, __fsub_rn(py, q2.w)),
                         __fmul_rn(q2.y, __fsub_rn(px, q2.z)));
    float b0 = __fmul_rn(w0, q3.w), b1 = __fmul_rn(w1, q3.w), b2 = __fmul_rn(w2, q3.w);
    float pc0 = b0 / q3.x, pc1 = b1 / q3.y, pc2 = b2 / q3.z;
    int i0 = f[best * 3 + 0], i1 = f[best * 3 + 1], i2 = f[best * 3 + 2];
    const float* c0p = vc + (size_t)i0 * 3;
    const float* c1p = vc + (size_t)i1 * 3;
    const float* c2p = vc + (size_t)i2 * 3;
    o0 = __fmul_rn(__fadd_rn(__fadd_rn(__fmul_rn(pc0, c0p[0]), __fmul_rn(pc1, c1p[0])),
                             __fmul_rn(pc2, c2p[0])), zmin);
    o1 = __fmul_rn(__fadd_rn(__fadd_rn(__fmul_rn(pc0, c0p[1]), __fmul_rn(pc1, c1p[1])),
                             __fmul_rn(pc2, c2p[1])), zmin);
    o2 = __fmul_rn(__fadd_rn(__fadd_rn(__fmul_rn(pc0, c0p[2]), __fmul_rn(pc1, c1p[2])),
                             __fmul_rn(pc2, c2p[2])), zmin);
  } else {
    o0 = bg[0]; o1 = bg[1]; o2 = bg[2];
  }
  size_t o = (size_t)p * 3;
  out[o + 0] = o0;
  out[o + 1] = o1;
  out[o + 2] = o2;
}

extern "C" void kernel_launch(void* const* d_in, const int* in_sizes, int n_in,
                              void* d_out, int out_size, void* d_ws, size_t ws_size,
                              hipStream_t stream) {
  const float* v   = (const float*)d_in[0];
  const float* vc  = (const float*)d_in[1];
  const float* bg  = (const float*)d_in[2];
  const float* cf  = (const float*)d_in[3];
  const float* cc  = (const float*)d_in[4];
  const float* ct  = (const float*)d_in[5];
  const float* crt = (const float*)d_in[6];
  const int*   f   = (const int*)d_in[7];
  float* out = (float*)d_out;
  char* ws = (char*)d_ws;

  float4*   verts = (float4*)(ws + OFF_VERTS);
  float*    zbU   = (float*)(ws + OFF_ZBU);
  float*    zbS   = (float*)(ws + OFF_ZBS);
  float4*   bbS   = (float4*)(ws + OFF_BBS);
  float4*   gmS   = (float4*)(ws + OFF_GMS);
  int*      oiS   = (int*)(ws + OFF_OIS);
  int*      inv   = (int*)(ws + OFF_INV);
  unsigned* chdr  = (unsigned*)(ws + OFF_CHDR);
  unsigned* cnt   = (unsigned*)(ws + OFF_CNT);
  unsigned* offs  = (unsigned*)(ws + OFF_OFFS);
  unsigned long long* keybuf = (unsigned long long*)(ws + OFF_KEY);

  hipLaunchKernelGGL(init_kernel, dim3((NB * HW + 255) / 256), dim3(256), 0, stream,
                     keybuf, zbS, bbS, chdr, cnt);
  hipLaunchKernelGGL(proj_kernel, dim3((NB * NV + 255) / 256), dim3(256), 0, stream,
                     v, cf, cc, ct, crt, verts);
  hipLaunchKernelGGL(zb_kernel, dim3((NB * NF + 255) / 256), dim3(256), 0, stream,
                     f, verts, zbU, cnt);
  hipLaunchKernelGGL(scan_kernel, dim3(NB), dim3(1024), 0, stream, cnt, offs);
  hipLaunchKernelGGL(scatter_kernel, dim3((NB * NF + 255) / 256), dim3(256), 0, stream,
                     f, verts, zbU, offs, zbS, bbS, gmS, oiS, inv, chdr);
  hipLaunchKernelGGL(suffix_kernel, dim3(NB), dim3(CHDR_STRIDE), 0, stream, chdr);
  hipLaunchKernelGGL(raster_kernel, dim3(W_IMG / 8, H_IMG / 8, NB),
                     dim3(256), 0, stream, chdr, zbS, bbS, gmS, oiS, keybuf);
  hipLaunchKernelGGL(shade_kernel, dim3((NB * HW + 255) / 256), dim3(256), 0, stream,
                     keybuf, gmS, inv, f, vc, bg, out);
}

// Round 10
// 333.884 us; speedup vs baseline: 10.2041x; 1.6687x over previous
//
#include <hip/hip_runtime.h>
#include <math.h>

#define H_IMG 224
#define W_IMG 224
#define HW (H_IMG * W_IMG)
#define EPSF 1e-8f
#define NV 6890
#define NF 13776
#define NB 2
#define FCHUNK 128
#define NCHUNK ((NF + FCHUNK - 1) / FCHUNK)   // 108
#define FPAD (NCHUNK * FCHUNK)                // 13824
#define NBUCK 1024
#define CHDR_STRIDE 128
#define KEY_INIT 0x7F800000FFFFFFFFULL        // zp=+inf, idx=~0

// workspace byte offsets (256-aligned)
#define OFF_VERTS 0u                          // NB*NV*16      = 220,480
#define OFF_ZBU   220672u                     // NB*NF*4       = 110,208
#define OFF_ZBS   331008u                     // NB*FPAD*4     = 110,592
#define OFF_BBS   441600u                     // NB*FPAD*16    = 442,368
#define OFF_GMS   883968u                     // NB*FPAD*64    = 1,769,472
#define OFF_OIS   2653440u                    // NB*FPAD*4     = 110,592
#define OFF_INV   2764032u                    // NB*NF*4       = 110,208
#define OFF_CHDR  2874368u                    // NB*128*4      = 1,024
#define OFF_CNT   2875392u                    // NB*1024*4     = 8,192
#define OFF_OFFS  2883584u                    // NB*1024*4     = 8,192
#define OFF_KEY   2891776u                    // NB*HW*8       = 802,816  (end ~3.69 MB)

__device__ inline unsigned long long shfl_xor_u64(unsigned long long v, int m) {
  unsigned lo = (unsigned)v, hi = (unsigned)(v >> 32);
  lo = __shfl_xor(lo, m);
  hi = __shfl_xor(hi, m);
  return ((unsigned long long)hi << 32) | lo;
}

__global__ void proj_kernel(const float* __restrict__ v,
                            const float* __restrict__ cf,
                            const float* __restrict__ cc,
                            const float* __restrict__ ct,
                            const float* __restrict__ crt,
                            float4* __restrict__ verts) {
  int i = blockIdx.x * blockDim.x + threadIdx.x;
  if (i >= NB * NV) return;
  float r0 = crt[0], r1 = crt[1], r2 = crt[2];
  float ss = __fadd_rn(__fadd_rn(__fmul_rn(r0, r0), __fmul_rn(r1, r1)), __fmul_rn(r2, r2));
  float th = sqrtf(__fadd_rn(ss, 1e-12f));
  float kx = r0 / th, ky = r1 / th, kz = r2 / th;
  float c = cosf(th), s = sinf(th), oc = 1.0f - c;
  float R00 = c + oc * kx * kx,      R01 = oc * kx * ky - s * kz, R02 = oc * kx * kz + s * ky;
  float R10 = oc * ky * kx + s * kz, R11 = c + oc * ky * ky,      R12 = oc * ky * kz - s * kx;
  float R20 = oc * kz * kx - s * ky, R21 = oc * kz * ky + s * kx, R22 = c + oc * kz * kz;
  float x = v[i * 3 + 0], y = v[i * 3 + 1], z = v[i * 3 + 2];
  float xc = R00 * x + R01 * y + R02 * z + ct[0];
  float yc = R10 * x + R11 * y + R12 * z + ct[1];
  float zc = R20 * x + R21 * y + R22 * z + ct[2];
  float zs = fmaxf(zc, EPSF);
  float u = __fadd_rn(__fmul_rn(xc / zs, cf[0]), cc[0]);
  float w = __fadd_rn(__fmul_rn(yc / zs, cf[1]), cc[1]);
  verts[i] = make_float4(u, w, zc, 0.0f);
}

__global__ void init_kernel(unsigned long long* __restrict__ keybuf,
                            float* __restrict__ zbS, float4* __restrict__ bbS,
                            unsigned* __restrict__ chdr, unsigned* __restrict__ cnt) {
  int t = blockIdx.x * blockDim.x + threadIdx.x;
  if (t < NB * HW) keybuf[t] = KEY_INIT;
  if (t < NB * FPAD) {
    zbS[t] = 3e30f;                                      // pad: sorts last
    bbS[t] = make_float4(1e30f, -1e30f, 1e30f, -1e30f);  // always-miss -> prefilter kills
  }
  if (t < NB * CHDR_STRIDE) chdr[t] = 0x7F800000u;       // +inf bits
  if (t < NB * NBUCK) cnt[t] = 0u;
}

// Depth lower-bound per face + bucket histogram.
// zb <= zp guaranteed: zp = 1/(sum b_i/z_i) >= minz/(1+serr), serr ~ 3*werr/|area|
// with werr ~5 ulps of the largest edge-function product term. Tight bound
// (slack 1e-3) only when 3*werr <= 5e-4*|area|; else zb=0 (never depth-culled).
__global__ void zb_kernel(const int* __restrict__ f, const float4* __restrict__ verts,
                          float* __restrict__ zbU, unsigned* __restrict__ cnt) {
  int i = blockIdx.x * blockDim.x + threadIdx.x;
  if (i >= NB * NF) return;
  int b = i / NF, fi = i - b * NF;
  int i0 = f[fi * 3 + 0], i1 = f[fi * 3 + 1], i2 = f[fi * 3 + 2];
  float4 p0 = verts[b * NV + i0], p1 = verts[b * NV + i1], p2 = verts[b * NV + i2];
  float area = __fsub_rn(__fmul_rn(__fsub_rn(p1.x, p0.x), __fsub_rn(p2.y, p0.y)),
                         __fmul_rn(__fsub_rn(p1.y, p0.y), __fsub_rn(p2.x, p0.x)));
  bool nz = fabsf(area) > EPSF;
  bool zv = (p0.z > EPSF) && (p1.z > EPSF) && (p2.z > EPSF);
  bool ok = nz && zv;
  float zb;
  if (!ok) {
    zb = 3e30f;  // invalid: can never produce a hit (inv_z <= EPS); sorts last
  } else {
    float minz = fminf(fminf(fmaxf(p0.z, EPSF), fmaxf(p1.z, EPSF)), fmaxf(p2.z, EPSF));
    float M = fmaxf(fmaxf(fmaxf(fabsf(p0.x), fabsf(p0.y)), fmaxf(fabsf(p1.x), fabsf(p1.y))),
                    fmaxf(fabsf(p2.x), fabsf(p2.y)));
    float werr = (2.0f * M) * (M + 256.0f) * 6e-7f;
    bool tight = (3.0f * werr) <= (5e-4f * fabsf(area));
    zb = tight ? __fmul_rn(minz, 0.999f) : 0.0f;
  }
  zbU[i] = zb;
  int bucket = (int)fminf(fmaxf(zb * 256.0f, 0.0f), (float)(NBUCK - 1));
  atomicAdd(&cnt[b * NBUCK + bucket], 1u);
}

__global__ __launch_bounds__(1024) void scan_kernel(const unsigned* __restrict__ cnt,
                                                    unsigned* __restrict__ offs) {
  __shared__ unsigned s[NBUCK];
  int t = threadIdx.x;
  int b = blockIdx.x;  // one block per batch
  unsigned v = cnt[b * NBUCK + t];
  s[t] = v;
  __syncthreads();
  unsigned acc = v;
  for (int d = 1; d < NBUCK; d <<= 1) {
    unsigned add = (t >= d) ? s[t - d] : 0u;
    __syncthreads();
    acc += add;
    s[t] = acc;
    __syncthreads();
  }
  offs[b * NBUCK + t] = acc - v;  // exclusive
}

// Scatter into depth-sorted SoA. Record values use the exact reference fp32 op
// sequence -> bit-identical results regardless of within-bucket position.
__global__ void scatter_kernel(const int* __restrict__ f, const float4* __restrict__ verts,
                               const float* __restrict__ zbU, unsigned* __restrict__ offs,
                               float* __restrict__ zbS, float4* __restrict__ bbS,
                               float4* __restrict__ gmS, int* __restrict__ oiS,
                               int* __restrict__ inv, unsigned* __restrict__ chdr) {
  int i = blockIdx.x * blockDim.x + threadIdx.x;
  if (i >= NB * NF) return;
  int b = i / NF, fi = i - b * NF;
  float zb = zbU[i];
  int bucket = (int)fminf(fmaxf(zb * 256.0f, 0.0f), (float)(NBUCK - 1));
  unsigned pos = atomicAdd(&offs[b * NBUCK + bucket], 1u);
  int i0 = f[fi * 3 + 0], i1 = f[fi * 3 + 1], i2 = f[fi * 3 + 2];
  float4 p0 = verts[b * NV + i0], p1 = verts[b * NV + i1], p2 = verts[b * NV + i2];
  float x0 = p0.x, y0 = p0.y, z0 = p0.z;
  float x1 = p1.x, y1 = p1.y, z1 = p1.z;
  float x2 = p2.x, y2 = p2.y, z2 = p2.z;
  float area = __fsub_rn(__fmul_rn(__fsub_rn(x1, x0), __fsub_rn(y2, y0)),
                         __fmul_rn(__fsub_rn(y1, y0), __fsub_rn(x2, x0)));
  bool nz = fabsf(area) > EPSF;
  float inv_area = nz ? (1.0f / area) : 0.0f;
  bool zv = (z0 > EPSF) && (z1 > EPSF) && (z2 > EPSF);
  bool ok = nz && zv;
  float zz0 = ok ? fmaxf(z0, EPSF) : 1e30f;
  float zz1 = ok ? fmaxf(z1, EPSF) : 1e30f;
  float zz2 = ok ? fmaxf(z2, EPSF) : 1e30f;
  size_t sp_ = (size_t)b * FPAD + pos;
  zbS[sp_] = zb;
  bbS[sp_] = make_float4(fminf(fminf(x0, x1), x2), fmaxf(fmaxf(x0, x1), x2),
                         fminf(fminf(y0, y1), y2), fmaxf(fmaxf(y0, y1), y2));
  gmS[sp_ * 4 + 0] = make_float4(__fsub_rn(x2, x1), __fsub_rn(y2, y1), x1, y1);
  gmS[sp_ * 4 + 1] = make_float4(__fsub_rn(x0, x2), __fsub_rn(y0, y2), x2, y2);
  gmS[sp_ * 4 + 2] = make_float4(__fsub_rn(x1, x0), __fsub_rn(y1, y0), x0, y0);
  gmS[sp_ * 4 + 3] = make_float4(zz0, zz1, zz2, inv_area);
  oiS[sp_] = fi;
  inv[i] = (int)pos;
  atomicMin(&chdr[b * CHDR_STRIDE + (int)(pos / FCHUNK)], __float_as_uint(zb));
}

// Suffix-min over chunk headers: chdr[c] := min over chunks >= c (uint min is
// order-preserving for nonnegative floats) -> raster break is conservative.
__global__ __launch_bounds__(CHDR_STRIDE) void suffix_kernel(unsigned* __restrict__ chdr) {
  __shared__ unsigned s[CHDR_STRIDE];
  int t = threadIdx.x, b = blockIdx.x;
  s[t] = chdr[b * CHDR_STRIDE + t];
  __syncthreads();
  for (int d = 1; d < CHDR_STRIDE; d <<= 1) {
    unsigned v = (t + d < CHDR_STRIDE) ? s[t + d] : 0x7F800000u;
    __syncthreads();
    s[t] = (v < s[t]) ? v : s[t];
    __syncthreads();
  }
  chdr[b * CHDR_STRIDE + t] = s[t];
}

// Block = 256 threads = 4 independent waves; each wave owns a 4x4 pixel tile
// (16 pixels x 4 face-slots). Prefilter (per 64-face half-chunk): lane loads
// its face's zb AND bbox (coalesced), pass = depth-pass && bbox-overlaps-TILE;
// one __ballot -> candidate mask. Tile-level bbox reject implies per-pixel
// bbox reject for every tile pixel -> strictly conservative. Eval goes
// STRAIGHT to edges (inside <=> b0,b1,b2>=0 implies bbox containment, so the
// per-pixel bbox test is redundant for correctness) — one fewer dependent
// load level. chdr[c] = suffix min -> first all-pixel failure breaks.
// Winner = commutative min of (zp_bits<<32)|orig_idx; bit-exact ref math.
__global__ __launch_bounds__(256) void raster_kernel(
    const unsigned* __restrict__ chdr,
    const float* __restrict__ zbS,
    const float4* __restrict__ bbS,
    const float4* __restrict__ gmS,
    const int* __restrict__ oiS,
    unsigned long long* __restrict__ keybuf) {
  int b = blockIdx.z;
  int w = threadIdx.x >> 6;                // wave 0..3 -> 2x2 tile grid
  int lane = threadIdx.x & 63;
  int slot = lane & 3;
  int p = lane >> 2;                       // 0..15
  int wx = (blockIdx.x * 2 + (w & 1)) * 4;
  int wy = (blockIdx.y * 2 + (w >> 1)) * 4;
  int x = wx + (p & 3);
  int y = wy + (p >> 2);
  float px = (float)x + 0.5f, py = (float)y + 0.5f;
  float tx0 = (float)wx + 0.5f, tx1 = (float)wx + 3.5f;   // tile pixel-center rect
  float ty0 = (float)wy + 0.5f, ty1 = (float)wy + 3.5f;
  const unsigned* chdrB = chdr + b * CHDR_STRIDE;
  const float*  zbB = zbS + (size_t)b * FPAD;
  const float4* bbB = bbS + (size_t)b * FPAD;
  const float4* gmB = gmS + (size_t)b * FPAD * 4;
  const int*    oiB = oiS + (size_t)b * FPAD;

  unsigned long long bestKey = KEY_INIT;

  for (int c = 0; c < NCHUNK; ++c) {
    float bz = __uint_as_float((unsigned)(bestKey >> 32));
    float comb = fminf(bz, __shfl_xor(bz, 1));        // min over 4 slots = pixel best
    comb = fminf(comb, __shfl_xor(comb, 2));
    float czb = __uint_as_float(chdrB[c]);            // suffix min over chunks >= c
    if (!__any(czb <= comb)) break;
    float combMax = fmaxf(comb, __shfl_xor(comb, 4)); // max over 16 pixels
    combMax = fmaxf(combMax, __shfl_xor(combMax, 8));
    combMax = fmaxf(combMax, __shfl_xor(combMax, 16));
    combMax = fmaxf(combMax, __shfl_xor(combMax, 32));
    int base = c * FCHUNK;
    #pragma unroll
    for (int h = 0; h < FCHUNK / 64; ++h) {
      int fbase = base + h * 64;
      float zb_lane = zbB[fbase + lane];              // coalesced, 1 per 64 faces
      float4 bb = bbB[fbase + lane];                  // coalesced bbox
      bool pass = (zb_lane <= combMax) &&
                  (bb.x <= tx1) && (bb.y >= tx0) &&   // bbox overlaps tile rect
                  (bb.z <= ty1) && (bb.w >= ty0);
      unsigned long long m = __ballot(pass);
      unsigned long long mm = m;
      while (mm) {
        int bit = __builtin_ctzll(mm);
        int g = bit & ~3;                             // nibble = 4-face group
        mm &= ~(0xFULL << g);
        if ((m >> (g + slot)) & 1) {
          int fi = fbase + g + slot;
          const float4* gm = &gmB[(size_t)fi * 4];
          float4 q0 = gm[0], q1 = gm[1], q2 = gm[2], q3 = gm[3];
          float w0 = __fsub_rn(__fmul_rn(q0.x, __fsub_rn(py, q0.w)),
                               __fmul_rn(q0.y, __fsub_rn(px, q0.z)));
          float w1 = __fsub_rn(__fmul_rn(q1.x, __fsub_rn(py, q1.w)),
                               __fmul_rn(q1.y, __fsub_rn(px, q1.z)));
          float w2 = __fsub_rn(__fmul_rn(q2.x, __fsub_rn(py, q2.w)),
                               __fmul_rn(q2.y, __fsub_rn(px, q2.z)));
          float b0 = __fmul_rn(w0, q3.w);
          float b1 = __fmul_rn(w1, q3.w);
          float b2 = __fmul_rn(w2, q3.w);
          if (b0 >= 0.0f && b1 >= 0.0f && b2 >= 0.0f) {
            float invz = __fadd_rn(__fadd_rn(b0 / q3.x, b1 / q3.y), b2 / q3.z);
            if (invz > EPSF) {
              float zp = 1.0f / invz;
              unsigned long long key =
                  ((unsigned long long)__float_as_uint(zp) << 32) | (unsigned)oiB[fi];
              if (key < bestKey) bestKey = key;
            }
          }
        }
      }
    }
  }

  // merge slots within each pixel quad
  unsigned long long o = shfl_xor_u64(bestKey, 1);
  if (o < bestKey) bestKey = o;
  o = shfl_xor_u64(bestKey, 2);
  if (o < bestKey) bestKey = o;
  if (slot == 0 && bestKey != KEY_INIT)
    atomicMin(&keybuf[(size_t)b * HW + (size_t)y * W_IMG + x], bestKey);
}

__global__ void shade_kernel(const unsigned long long* __restrict__ keybuf,
                             const float4* __restrict__ gmS,
                             const int* __restrict__ inv,
                             const int* __restrict__ f,
                             const float* __restrict__ vc,
                             const float* __restrict__ bg,
                             float* __restrict__ out) {
  int p = blockIdx.x * blockDim.x + threadIdx.x;
  if (p >= NB * HW) return;
  int b = p / HW, pix = p - b * HW;
  int y = pix / W_IMG, x = pix - y * W_IMG;
  float px = (float)x + 0.5f, py = (float)y + 0.5f;
  unsigned long long key = keybuf[p];
  float o0, o1, o2;
  if (key != KEY_INIT) {
    int best = (int)(unsigned)(key & 0xFFFFFFFFu);
    float zmin = __uint_as_float((unsigned)(key >> 32));
    int pos = inv[b * NF + best];
    const float4* g = &gmS[((size_t)b * FPAD + pos) * 4];
    float4 q0 = g[0], q1 = g[1], q2 = g[2], q3 = g[3];
    float w0 = __fsub_rn(__fmul_rn(q0.x, __fsub_rn(py, q0.w)),
                         __fmul_rn(q0.y, __fsub_rn(px, q0.z)));
    float w1 = __fsub_rn(__fmul_rn(q1.x, __fsub_rn(py, q1.w)),
                         __fmul_rn(q1.y, __fsub_rn(px, q1.z)));
    float w2 = __fsub_rn(__fmul_rn(q2.x, __fsub_rn(py, q2.w)),
                         __fmul_rn(q2.y, __fsub_rn(px, q2.z)));
    float b0 = __fmul_rn(w0, q3.w), b1 = __fmul_rn(w1, q3.w), b2 = __fmul_rn(w2, q3.w);
    float pc0 = b0 / q3.x, pc1 = b1 / q3.y, pc2 = b2 / q3.z;
    int i0 = f[best * 3 + 0], i1 = f[best * 3 + 1], i2 = f[best * 3 + 2];
    const float* c0p = vc + (size_t)i0 * 3;
    const float* c1p = vc + (size_t)i1 * 3;
    const float* c2p = vc + (size_t)i2 * 3;
    o0 = __fmul_rn(__fadd_rn(__fadd_rn(__fmul_rn(pc0, c0p[0]), __fmul_rn(pc1, c1p[0])),
                             __fmul_rn(pc2, c2p[0])), zmin);
    o1 = __fmul_rn(__fadd_rn(__fadd_rn(__fmul_rn(pc0, c0p[1]), __fmul_rn(pc1, c1p[1])),
                             __fmul_rn(pc2, c2p[1])), zmin);
    o2 = __fmul_rn(__fadd_rn(__fadd_rn(__fmul_rn(pc0, c0p[2]), __fmul_rn(pc1, c1p[2])),
                             __fmul_rn(pc2, c2p[2])), zmin);
  } else {
    o0 = bg[0]; o1 = bg[1]; o2 = bg[2];
  }
  size_t o = (size_t)p * 3;
  out[o + 0] = o0;
  out[o + 1] = o1;
  out[o + 2] = o2;
}

extern "C" void kernel_launch(void* const* d_in, const int* in_sizes, int n_in,
                              void* d_out, int out_size, void* d_ws, size_t ws_size,
                              hipStream_t stream) {
  const float* v   = (const float*)d_in[0];
  const float* vc  = (const float*)d_in[1];
  const float* bg  = (const float*)d_in[2];
  const float* cf  = (const float*)d_in[3];
  const float* cc  = (const float*)d_in[4];
  const float* ct  = (const float*)d_in[5];
  const float* crt = (const float*)d_in[6];
  const int*   f   = (const int*)d_in[7];
  float* out = (float*)d_out;
  char* ws = (char*)d_ws;

  float4*   verts = (float4*)(ws + OFF_VERTS);
  float*    zbU   = (float*)(ws + OFF_ZBU);
  float*    zbS   = (float*)(ws + OFF_ZBS);
  float4*   bbS   = (float4*)(ws + OFF_BBS);
  float4*   gmS   = (float4*)(ws + OFF_GMS);
  int*      oiS   = (int*)(ws + OFF_OIS);
  int*      inv   = (int*)(ws + OFF_INV);
  unsigned* chdr  = (unsigned*)(ws + OFF_CHDR);
  unsigned* cnt   = (unsigned*)(ws + OFF_CNT);
  unsigned* offs  = (unsigned*)(ws + OFF_OFFS);
  unsigned long long* keybuf = (unsigned long long*)(ws + OFF_KEY);

  hipLaunchKernelGGL(init_kernel, dim3((NB * HW + 255) / 256), dim3(256), 0, stream,
                     keybuf, zbS, bbS, chdr, cnt);
  hipLaunchKernelGGL(proj_kernel, dim3((NB * NV + 255) / 256), dim3(256), 0, stream,
                     v, cf, cc, ct, crt, verts);
  hipLaunchKernelGGL(zb_kernel, dim3((NB * NF + 255) / 256), dim3(256), 0, stream,
                     f, verts, zbU, cnt);
  hipLaunchKernelGGL(scan_kernel, dim3(NB), dim3(1024), 0, stream, cnt, offs);
  hipLaunchKernelGGL(scatter_kernel, dim3((NB * NF + 255) / 256), dim3(256), 0, stream,
                     f, verts, zbU, offs, zbS, bbS, gmS, oiS, inv, chdr);
  hipLaunchKernelGGL(suffix_kernel, dim3(NB), dim3(CHDR_STRIDE), 0, stream, chdr);
  hipLaunchKernelGGL(raster_kernel, dim3(W_IMG / 8, H_IMG / 8, NB),
                     dim3(256), 0, stream, chdr, zbS, bbS, gmS, oiS, keybuf);
  hipLaunchKernelGGL(shade_kernel, dim3((NB * HW + 255) / 256), dim3(256), 0, stream,
                     keybuf, gmS, inv, f, vc, bg, out);
}